// Round 13
// baseline (104.290 us; speedup 1.0000x reference)
//
#include <hip/hip_runtime.h>

constexpr int Hh = 320, Ww = 320, Cc = 32, Bb = 4, Nn = 20000;
constexpr int HWp = Hh * Ww;

// Quad-group (4-lane) butterfly adds via DPP quad_perm -- VALU, no LDS pipe.
// xor1: lanes [1,0,3,2] = 0xB1; xor2: lanes [2,3,0,1] = 0x4E.
__device__ __forceinline__ float quad_add_xor1(float x) {
  int v = __builtin_amdgcn_update_dpp(0, __float_as_int(x), 0xB1, 0xF, 0xF, true);
  return x + __int_as_float(v);
}
__device__ __forceinline__ float quad_add_xor2(float x) {
  int v = __builtin_amdgcn_update_dpp(0, __float_as_int(x), 0x4E, 0xF, 0xF, true);
  return x + __int_as_float(v);
}

// prep: pure grid fill with -1 (int4 stores, full BW).
__global__ __launch_bounds__(256) void prep_k(int* __restrict__ grids) {
  int i = blockIdx.x * 256 + threadIdx.x;  // 800*256 int4 = 2*4*HWp ints exact
  ((int4*)grids)[i] = make_int4(-1, -1, -1, -1);
}

// Fused: blocks [0, PROJ_TOTAL) = Q/K/V projection (register-tiled, 4 pts/thread);
// blocks [PROJ_TOTAL, +BUILD_BLOCKS) = build_grid scatter (grid pre-filled);
// last 3 blocks = posv[dir][l][c] = pos[l] @ wv_dir.T.
// K is pre-scaled by 0.25 (= 1/sqrt(HD)) so attn needs no score scaling.
constexpr int PROJ_BLOCKS_PER_SB = 157;              // ceil(20000/128)
constexpr int PROJ_TOTAL = PROJ_BLOCKS_PER_SB * 8;   // 1256
constexpr int BUILD_BLOCKS = 625;                    // 160000/256 exact

__global__ __launch_bounds__(256) void project_build_k(
    const float* __restrict__ li_feats, const float* __restrict__ ra_feats,
    const int* __restrict__ li_coors, const int* __restrict__ ra_coors,
    const float* __restrict__ pos,
    const float* __restrict__ in_w1, const float* __restrict__ in_b1,
    const float* __restrict__ in_w2, const float* __restrict__ in_b2,
    float* __restrict__ Qh, float* __restrict__ Kp, float* __restrict__ Vp,
    int* __restrict__ grids, float* __restrict__ posv) {
  int bx = blockIdx.x;
  if (bx >= PROJ_TOTAL) {
    if (bx < PROJ_TOTAL + BUILD_BLOCKS) {
      int idx = (bx - PROJ_TOTAL) * 256 + threadIdx.x;  // [0, 160000) exact
      int src = idx / (Bb * Nn);
      int r = idx - src * (Bb * Nn);
      int b = r / Nn, n = r - b * Nn;
      const int* c = (src == 0 ? li_coors : ra_coors) + ((size_t)b * Nn + n) * 2;
      grids[((size_t)src * Bb + b) * HWp + c[0] * Ww + c[1]] = n;
    } else {
      int tt = (bx - PROJ_TOTAL - BUILD_BLOCKS) * 256 + threadIdx.x;
      if (tt < 2 * 9 * Cc) {
        int dir = tt / (9 * Cc);
        int rem = tt - dir * 9 * Cc;
        int l = rem / Cc, ch = rem - l * Cc;
        const float* w = (dir == 0 ? in_w1 : in_w2) + (2 * Cc + ch) * Cc;
        const float* pl = pos + l * Cc;
        float acc = 0.f;
        for (int j = 0; j < Cc; j++) acc += pl[j] * w[j];
        posv[tt] = acc;
      }
    }
    return;
  }
  int sb = bx / PROJ_BLOCKS_PER_SB;
  int blk = bx - sb * PROJ_BLOCKS_PER_SB;
  int src = sb >> 2, b = sb & 3;
  // weights transposed, rows padded to 36 floats (9 float4) for bank spread
  __shared__ __align__(16) float wqT[32 * 36];
  __shared__ __align__(16) float wkT[32 * 36];
  __shared__ __align__(16) float wvT[32 * 36];
  __shared__ float bq[Cc];
  const float* wA = src == 0 ? in_w1 : in_w2;  // q weights: own direction
  const float* bA = src == 0 ? in_b1 : in_b2;
  const float* wB = src == 0 ? in_w2 : in_w1;  // k/v weights: other direction
  int t = threadIdx.x;
  for (int i = t; i < Cc * Cc; i += 256) {
    int c = i >> 5, j = i & 31;
    wqT[j * 36 + c] = wA[i];
    wkT[j * 36 + c] = 0.25f * wB[Cc * Cc + i];  // fold 1/sqrt(HD)
    wvT[j * 36 + c] = wB[2 * Cc * Cc + i];
  }
  if (t < Cc) bq[t] = bA[t];
  __syncthreads();
  int quad = t >> 3, c4 = t & 7;
  int n0 = blk * 128 + quad * 4;
  if (n0 + 4 > Nn) n0 = Nn - 4;  // tail clamp: redundant idempotent work
  const float* f = (src == 0 ? li_feats : ra_feats) + ((size_t)b * Nn + n0) * Cc;
  const float4* wq4 = (const float4*)wqT;
  const float4* wk4 = (const float4*)wkT;
  const float4* wv4 = (const float4*)wvT;
  float4 bq4 = *(const float4*)(bq + c4 * 4);
  float4 aq[4], ak[4], av[4];
#pragma unroll
  for (int i = 0; i < 4; i++) {
    aq[i] = bq4;
    ak[i] = make_float4(0.f, 0.f, 0.f, 0.f);
    av[i] = make_float4(0.f, 0.f, 0.f, 0.f);
  }
#pragma unroll
  for (int j4 = 0; j4 < 8; j4++) {
    float fjs[4][4];
#pragma unroll
    for (int i = 0; i < 4; i++) {
      float4 v = ((const float4*)(f + i * Cc))[j4];
      fjs[i][0] = v.x; fjs[i][1] = v.y; fjs[i][2] = v.z; fjs[i][3] = v.w;
    }
#pragma unroll
    for (int u = 0; u < 4; u++) {
      int j = j4 * 4 + u;
      float4 q4 = wq4[j * 9 + c4];
      float4 k4 = wk4[j * 9 + c4];
      float4 v4 = wv4[j * 9 + c4];
#pragma unroll
      for (int i = 0; i < 4; i++) {
        float fj = fjs[i][u];
        aq[i].x += fj * q4.x; aq[i].y += fj * q4.y;
        aq[i].z += fj * q4.z; aq[i].w += fj * q4.w;
        ak[i].x += fj * k4.x; ak[i].y += fj * k4.y;
        ak[i].z += fj * k4.z; ak[i].w += fj * k4.w;
        av[i].x += fj * v4.x; av[i].y += fj * v4.y;
        av[i].z += fj * v4.z; av[i].w += fj * v4.w;
      }
    }
  }
  int dirkv = 1 - src;
  size_t qbase = (((size_t)src * Bb + b) * Nn + n0) * Cc + c4 * 4;
  size_t kvbase = (((size_t)dirkv * Bb + b) * Nn + n0) * Cc + c4 * 4;
#pragma unroll
  for (int i = 0; i < 4; i++) {
    *(float4*)(Qh + qbase + i * Cc) = aq[i];
    *(float4*)(Kp + kvbase + i * Cc) = ak[i];
    *(float4*)(Vp + kvbase + i * Cc) = av[i];
  }
}

// 8-lane-per-point attention + output projection.
// DS-pipe-minimized: head-group reductions use DPP quad_perm (VALU, no LDS);
// out-projection stages o in padded LDS and loops absolute j-quads (no
// shuffles). All 18 K/V gathers issued upfront into registers (r10-proven).
__global__ __launch_bounds__(256) void attn8_k(
    const int* __restrict__ li_coors, const int* __restrict__ ra_coors,
    const int* __restrict__ grids, const float* __restrict__ Qh,
    const float* __restrict__ Kp, const float* __restrict__ Vp,
    const float* __restrict__ posv, const float* __restrict__ in_b1,
    const float* __restrict__ in_b2, const float* __restrict__ out_w1,
    const float* __restrict__ out_b1, const float* __restrict__ out_w2,
    const float* __restrict__ out_b2, float* __restrict__ out_pts) {
  int db = blockIdx.y;
  int dir = db >> 2, b = db & 3;
  __shared__ __align__(16) float ow[Cc * Cc];
  __shared__ __align__(16) float pv[9 * Cc];
  __shared__ __align__(16) float o_lds[32 * 36];  // 32 points x padded 36
  __shared__ float sbk[Cc], sbv[Cc], sob[Cc];
  const float* owp = dir == 0 ? out_w1 : out_w2;
  const float* obp = dir == 0 ? out_b1 : out_b2;
  const float* ibp = dir == 0 ? in_b1 : in_b2;
  int t = threadIdx.x;
  for (int i = t; i < Cc * Cc; i += 256) ow[i] = owp[i];
  for (int i = t; i < 9 * Cc; i += 256) pv[i] = posv[dir * 9 * Cc + i];
  if (t < Cc) {
    sbk[t] = 0.25f * ibp[Cc + t];  // fold 1/sqrt(HD) (K pre-scaled too)
    sbv[t] = ibp[2 * Cc + t];
    sob[t] = obp[t];
  }
  __syncthreads();
  int pt = t >> 3, c4 = t & 7;
  int n = blockIdx.x * 32 + pt;  // 625*32 == 20000 exact, no tail
  // ---- issue Qh load first (independent; in flight during addr calc)
  float4 qh4 =
      *(const float4*)(Qh + (((size_t)dir * Bb + b) * Nn + n) * Cc + c4 * 4);
  const int2* qcp =
      (const int2*)((dir == 0 ? li_coors : ra_coors) + (size_t)b * Nn * 2);
  int2 yx = qcp[n];
  int y = yx.x, x = yx.y;
  const int* g = grids + ((size_t)(1 - dir) * Bb + b) * HWp;
  const int DY[9] = {0, -1, 1, 0, -1, 1, 0, -1, 1};
  const int DX[9] = {0, 0, 0, 1, 1, 1, -1, -1, -1};
  // ---- phase 1: all 9 sel loads (independent, 1-deep; grid pre-filled)
  int sel[9];
#pragma unroll
  for (int l = 0; l < 9; l++) {
    int cy = y + DY[l], cx = x + DX[l];
    sel[l] = ((unsigned)cy < (unsigned)Hh && (unsigned)cx < (unsigned)Ww)
                 ? g[cy * Ww + cx]
                 : -1;
  }
  // ---- phase 2: issue all K/V gathers into registers (zero when invalid)
  const float* Kpb = Kp + ((size_t)dir * Bb + b) * Nn * Cc;
  const float* Vpb = Vp + ((size_t)dir * Bb + b) * Nn * Cc;
  float4 k4s[9], v4s[9];
#pragma unroll
  for (int l = 0; l < 9; l++) {
    float4 kk = make_float4(0.f, 0.f, 0.f, 0.f);
    float4 vv = make_float4(0.f, 0.f, 0.f, 0.f);
    int se = sel[l];
    if (se >= 0) {
      kk = *(const float4*)(Kpb + (size_t)se * Cc + c4 * 4);
      vv = *(const float4*)(Vpb + (size_t)se * Cc + c4 * 4);
    }
    k4s[l] = kk;
    v4s[l] = vv;
  }
  // invalid-slot score: qh . bk_scaled over the lane's head (DPP reduce)
  float4 bk4 = *(const float4*)(sbk + c4 * 4);
  float pb = qh4.x * bk4.x + qh4.y * bk4.y + qh4.z * bk4.z + qh4.w * bk4.w;
  pb = quad_add_xor1(pb);
  pb = quad_add_xor2(pb);
  // ---- phase 3: scores from registers (K pre-scaled; k4s=0 invalid -> s=pb)
  float s[9];
#pragma unroll
  for (int l = 0; l < 9; l++) {
    float4 k4 = k4s[l];
    float d = qh4.x * k4.x + qh4.y * k4.y + qh4.z * k4.z + qh4.w * k4.w;
    d = quad_add_xor1(d);
    d = quad_add_xor2(d);  // lane's head dot
    s[l] = pb + d;
  }
  // softmax over 9 slots for the lane's head
  float m = s[0];
#pragma unroll
  for (int l = 1; l < 9; l++) m = fmaxf(m, s[l]);
  float sum = 0.f;
#pragma unroll
  for (int l = 0; l < 9; l++) {
    s[l] = __expf(s[l] - m);
    sum += s[l];
  }
  // ---- phase 4: PV from registers (posv only for valid slots)
  float4 o4 = make_float4(0.f, 0.f, 0.f, 0.f);
#pragma unroll
  for (int l = 0; l < 9; l++) {
    float wp = (sel[l] >= 0) ? s[l] : 0.f;
    float4 v4 = v4s[l];
    float4 p4 = *(const float4*)(pv + l * Cc + c4 * 4);
    o4.x += wp * (v4.x + p4.x);
    o4.y += wp * (v4.y + p4.y);
    o4.z += wp * (v4.z + p4.z);
    o4.w += wp * (v4.w + p4.w);
  }
  float r = 1.f / sum;
  float4 bv4 = *(const float4*)(sbv + c4 * 4);
  o4 = make_float4(o4.x * r + bv4.x, o4.y * r + bv4.y, o4.z * r + bv4.z,
                   o4.w * r + bv4.w);
  // ---- output projection: stage o in LDS, absolute-jb loop (no shuffles).
  // o-read banks: addr = pt*36 + jb*4 -> bank (pt*4+jb*4)%32, distinct per
  // pt-group at fixed jb; 8 lanes of a point broadcast the same address.
  *(float4*)(o_lds + pt * 36 + c4 * 4) = o4;
  __syncthreads();
  const float4* ow4 = (const float4*)ow;
  float4 sob4 = *(const float4*)(sob + c4 * 4);
  float acc0 = sob4.x, acc1 = sob4.y, acc2 = sob4.z, acc3 = sob4.w;
#pragma unroll
  for (int jb = 0; jb < 8; jb++) {
    float4 oj = *(const float4*)(o_lds + pt * 36 + jb * 4);
    float4 w0 = ow4[(c4 * 4 + 0) * 8 + jb];
    float4 w1 = ow4[(c4 * 4 + 1) * 8 + jb];
    float4 w2 = ow4[(c4 * 4 + 2) * 8 + jb];
    float4 w3 = ow4[(c4 * 4 + 3) * 8 + jb];
    acc0 += oj.x * w0.x + oj.y * w0.y + oj.z * w0.z + oj.w * w0.w;
    acc1 += oj.x * w1.x + oj.y * w1.y + oj.z * w1.z + oj.w * w1.w;
    acc2 += oj.x * w2.x + oj.y * w2.y + oj.z * w2.z + oj.w * w2.w;
    acc3 += oj.x * w3.x + oj.y * w3.y + oj.z * w3.z + oj.w * w3.w;
  }
  *(float4*)(out_pts + (((size_t)dir * Bb + b) * Nn + n) * Cc + c4 * 4) =
      make_float4(acc0, acc1, acc2, acc3);
}

// Inverted scatter: grid pre-filled, no verify. One thread per canvas pixel;
// channel stores are wave-coalesced full lines.
__global__ __launch_bounds__(256) void scatter_k(
    const int* __restrict__ grids, const float* __restrict__ out_pts,
    float* __restrict__ out) {
  int db = blockIdx.y;
  int dir = db >> 2, b = db & 3;
  int p = blockIdx.x * 256 + threadIdx.x;
  const int* gq = grids + ((size_t)dir * Bb + b) * HWp;
  int se = gq[p];
  float* ob = out + (((size_t)dir * Bb + b) * Cc) * HWp + p;
  if (se < 0) {
#pragma unroll
    for (int c = 0; c < Cc; c++) ob[(size_t)c * HWp] = 0.f;
  } else {
    const float4* sp =
        (const float4*)(out_pts + (((size_t)dir * Bb + b) * Nn + se) * Cc);
#pragma unroll
    for (int c4 = 0; c4 < 8; c4++) {
      float4 v = sp[c4];
      ob[(size_t)(c4 * 4 + 0) * HWp] = v.x;
      ob[(size_t)(c4 * 4 + 1) * HWp] = v.y;
      ob[(size_t)(c4 * 4 + 2) * HWp] = v.z;
      ob[(size_t)(c4 * 4 + 3) * HWp] = v.w;
    }
  }
}

extern "C" void kernel_launch(void* const* d_in, const int* in_sizes, int n_in,
                              void* d_out, int out_size, void* d_ws, size_t ws_size,
                              hipStream_t stream) {
  const float* li_feats = (const float*)d_in[0];
  const int* li_coors = (const int*)d_in[1];
  const float* ra_feats = (const float*)d_in[2];
  const int* ra_coors = (const int*)d_in[3];
  const float* pos = (const float*)d_in[4];
  const float* in_w1 = (const float*)d_in[5];
  const float* in_b1 = (const float*)d_in[6];
  const float* out_w1 = (const float*)d_in[7];
  const float* out_b1 = (const float*)d_in[8];
  const float* in_w2 = (const float*)d_in[9];
  const float* in_b2 = (const float*)d_in[10];
  const float* out_w2 = (const float*)d_in[11];
  const float* out_b2 = (const float*)d_in[12];

  char* ws = (char*)d_ws;
  size_t off = 0;
  int* grids = (int*)(ws + off);
  off += (size_t)2 * Bb * HWp * 4;  // 3,276,800 B
  float* Qh = (float*)(ws + off);
  off += (size_t)2 * Bb * Nn * Cc * 4;  // 20,480,000 B
  float* Kp = (float*)(ws + off);
  off += (size_t)2 * Bb * Nn * Cc * 4;
  float* Vp = (float*)(ws + off);
  off += (size_t)2 * Bb * Nn * Cc * 4;
  float* out_pts = (float*)(ws + off);
  off += (size_t)2 * Bb * Nn * Cc * 4;
  float* posv = (float*)(ws + off);
  off += 2 * 9 * Cc * 4;  // total ~85.2 MB

  prep_k<<<800, 256, 0, stream>>>(grids);
  project_build_k<<<PROJ_TOTAL + BUILD_BLOCKS + 3, 256, 0, stream>>>(
      li_feats, ra_feats, li_coors, ra_coors, pos, in_w1, in_b1, in_w2, in_b2,
      Qh, Kp, Vp, grids, posv);
  dim3 ga(Nn / 32, 2 * Bb);
  attn8_k<<<ga, 256, 0, stream>>>(li_coors, ra_coors, grids, Qh, Kp, Vp, posv,
                                  in_b1, in_b2, out_w1, out_b1, out_w2, out_b2,
                                  out_pts);
  dim3 gs(HWp / 256, 2 * Bb);
  scatter_k<<<gs, 256, 0, stream>>>(grids, out_pts, (float*)d_out);
}

// Round 14
// 94.547 us; speedup vs baseline: 1.1030x; 1.1030x over previous
//
#include <hip/hip_runtime.h>

constexpr int Hh = 320, Ww = 320, Cc = 32, Bb = 4, Nn = 20000;
constexpr int HWp = Hh * Ww;

__device__ __forceinline__ float4 shfl_xor4(float4 v, int m) {
  return make_float4(__shfl_xor(v.x, m), __shfl_xor(v.y, m),
                     __shfl_xor(v.z, m), __shfl_xor(v.w, m));
}

// prep: blocks [0,800) fill grids with -1 (int4, full BW); blocks [800,803)
// compute posv[dir][l][c] = pos[l] @ wv_dir.T
__global__ __launch_bounds__(256) void prep_k(
    int* __restrict__ grids, const float* __restrict__ pos,
    const float* __restrict__ in_w1, const float* __restrict__ in_w2,
    float* __restrict__ posv) {
  int bx = blockIdx.x;
  if (bx < 800) {
    int i = bx * 256 + threadIdx.x;  // 800*256 int4 = 2*4*HWp ints exactly
    ((int4*)grids)[i] = make_int4(-1, -1, -1, -1);
    return;
  }
  int t = (bx - 800) * 256 + threadIdx.x;
  if (t >= 2 * 9 * Cc) return;
  int dir = t / (9 * Cc);
  int rem = t - dir * 9 * Cc;
  int l = rem / Cc, ch = rem - l * Cc;
  const float* w = (dir == 0 ? in_w1 : in_w2) + (2 * Cc + ch) * Cc;
  const float* pl = pos + l * Cc;
  float acc = 0.f;
  for (int j = 0; j < Cc; j++) acc += pl[j] * w[j];
  posv[t] = acc;
}

// Fused: blocks [0, PROJ_TOTAL) = Q/K/V projection (register-tiled, 8 pts/thread
// -> halves the LDS-read waves vs 4-pt tile; DS pipe was project's bound);
// blocks [PROJ_TOTAL, +BUILD_BLOCKS) = build_grid scatter (grid pre-filled).
constexpr int PROJ_BLOCKS_PER_SB = 79;               // ceil(20000/256)
constexpr int PROJ_TOTAL = PROJ_BLOCKS_PER_SB * 8;   // 632
constexpr int BUILD_BLOCKS = 625;                    // 160000/256 exact

__global__ __launch_bounds__(256) void project_build_k(
    const float* __restrict__ li_feats, const float* __restrict__ ra_feats,
    const int* __restrict__ li_coors, const int* __restrict__ ra_coors,
    const float* __restrict__ in_w1, const float* __restrict__ in_b1,
    const float* __restrict__ in_w2, const float* __restrict__ in_b2,
    float* __restrict__ Qh, float* __restrict__ Kp, float* __restrict__ Vp,
    int* __restrict__ grids) {
  int bx = blockIdx.x;
  if (bx >= PROJ_TOTAL) {
    int idx = (bx - PROJ_TOTAL) * 256 + threadIdx.x;  // [0, 160000) exact
    int src = idx / (Bb * Nn);
    int r = idx - src * (Bb * Nn);
    int b = r / Nn, n = r - b * Nn;
    const int* c = (src == 0 ? li_coors : ra_coors) + ((size_t)b * Nn + n) * 2;
    grids[((size_t)src * Bb + b) * HWp + c[0] * Ww + c[1]] = n;
    return;
  }
  int sb = bx / PROJ_BLOCKS_PER_SB;
  int blk = bx - sb * PROJ_BLOCKS_PER_SB;
  int src = sb >> 2, b = sb & 3;
  // weights transposed, rows padded to 36 floats (9 float4) for bank spread
  __shared__ __align__(16) float wqT[32 * 36];
  __shared__ __align__(16) float wkT[32 * 36];
  __shared__ __align__(16) float wvT[32 * 36];
  __shared__ float bq[Cc];
  const float* wA = src == 0 ? in_w1 : in_w2;  // q weights: own direction
  const float* bA = src == 0 ? in_b1 : in_b2;
  const float* wB = src == 0 ? in_w2 : in_w1;  // k/v weights: other direction
  int t = threadIdx.x;
  for (int i = t; i < Cc * Cc; i += 256) {
    int c = i >> 5, j = i & 31;
    wqT[j * 36 + c] = wA[i];
    wkT[j * 36 + c] = wB[Cc * Cc + i];
    wvT[j * 36 + c] = wB[2 * Cc * Cc + i];
  }
  if (t < Cc) bq[t] = bA[t];
  __syncthreads();
  int grp = t >> 3, c4 = t & 7;
  int n0 = blk * 256 + grp * 8;
  if (n0 + 8 > Nn) n0 = Nn - 8;  // tail clamp: redundant idempotent work
  const float* f = (src == 0 ? li_feats : ra_feats) + ((size_t)b * Nn + n0) * Cc;
  const float4* wq4 = (const float4*)wqT;
  const float4* wk4 = (const float4*)wkT;
  const float4* wv4 = (const float4*)wvT;
  float4 bq4 = *(const float4*)(bq + c4 * 4);
  float4 aq[8], ak[8], av[8];
#pragma unroll
  for (int i = 0; i < 8; i++) {
    aq[i] = bq4;
    ak[i] = make_float4(0.f, 0.f, 0.f, 0.f);
    av[i] = make_float4(0.f, 0.f, 0.f, 0.f);
  }
#pragma unroll
  for (int j4 = 0; j4 < 8; j4++) {
    float fjs[8][4];
#pragma unroll
    for (int i = 0; i < 8; i++) {
      float4 v = ((const float4*)(f + i * Cc))[j4];
      fjs[i][0] = v.x; fjs[i][1] = v.y; fjs[i][2] = v.z; fjs[i][3] = v.w;
    }
#pragma unroll
    for (int u = 0; u < 4; u++) {
      int j = j4 * 4 + u;
      float4 q4 = wq4[j * 9 + c4];
      float4 k4 = wk4[j * 9 + c4];
      float4 v4 = wv4[j * 9 + c4];
#pragma unroll
      for (int i = 0; i < 8; i++) {
        float fj = fjs[i][u];
        aq[i].x += fj * q4.x; aq[i].y += fj * q4.y;
        aq[i].z += fj * q4.z; aq[i].w += fj * q4.w;
        ak[i].x += fj * k4.x; ak[i].y += fj * k4.y;
        ak[i].z += fj * k4.z; ak[i].w += fj * k4.w;
        av[i].x += fj * v4.x; av[i].y += fj * v4.y;
        av[i].z += fj * v4.z; av[i].w += fj * v4.w;
      }
    }
  }
  int dirkv = 1 - src;
  size_t qbase = (((size_t)src * Bb + b) * Nn + n0) * Cc + c4 * 4;
  size_t kvbase = (((size_t)dirkv * Bb + b) * Nn + n0) * Cc + c4 * 4;
#pragma unroll
  for (int i = 0; i < 8; i++) {
    *(float4*)(Qh + qbase + i * Cc) = aq[i];
    *(float4*)(Kp + kvbase + i * Cc) = ak[i];
    *(float4*)(Vp + kvbase + i * Cc) = av[i];
  }
}

// 8-lane-per-point attention + in-kernel output projection. (r10-proven form:
// all 9 sel loads 1-deep, then ALL 18 K/V gathers upfront into registers,
// then dots/softmax/PV from registers.) Lane owns channels [4*c4, 4*c4+4).
__global__ __launch_bounds__(256) void attn8_k(
    const int* __restrict__ li_coors, const int* __restrict__ ra_coors,
    const int* __restrict__ grids, const float* __restrict__ Qh,
    const float* __restrict__ Kp, const float* __restrict__ Vp,
    const float* __restrict__ posv, const float* __restrict__ in_b1,
    const float* __restrict__ in_b2, const float* __restrict__ out_w1,
    const float* __restrict__ out_b1, const float* __restrict__ out_w2,
    const float* __restrict__ out_b2, float* __restrict__ out_pts) {
  int db = blockIdx.y;
  int dir = db >> 2, b = db & 3;
  __shared__ __align__(16) float ow[Cc * Cc];
  __shared__ __align__(16) float pv[9 * Cc];
  __shared__ float sbk[Cc], sbv[Cc], sob[Cc];
  const float* owp = dir == 0 ? out_w1 : out_w2;
  const float* obp = dir == 0 ? out_b1 : out_b2;
  const float* ibp = dir == 0 ? in_b1 : in_b2;
  int t = threadIdx.x;
  for (int i = t; i < Cc * Cc; i += 256) ow[i] = owp[i];
  for (int i = t; i < 9 * Cc; i += 256) pv[i] = posv[dir * 9 * Cc + i];
  if (t < Cc) {
    sbk[t] = ibp[Cc + t];
    sbv[t] = ibp[2 * Cc + t];
    sob[t] = obp[t];
  }
  __syncthreads();
  int pt = t >> 3, c4 = t & 7;
  int n = blockIdx.x * 32 + pt;  // 625*32 == 20000 exact, no tail
  const int2* qcp =
      (const int2*)((dir == 0 ? li_coors : ra_coors) + (size_t)b * Nn * 2);
  int2 yx = qcp[n];
  int y = yx.x, x = yx.y;
  const int* g = grids + ((size_t)(1 - dir) * Bb + b) * HWp;
  const int DY[9] = {0, -1, 1, 0, -1, 1, 0, -1, 1};
  const int DX[9] = {0, 0, 0, 1, 1, 1, -1, -1, -1};
  // ---- phase 1: all 9 sel loads (independent, 1-deep; grid pre-filled)
  int sel[9];
#pragma unroll
  for (int l = 0; l < 9; l++) {
    int cy = y + DY[l], cx = x + DX[l];
    sel[l] = ((unsigned)cy < (unsigned)Hh && (unsigned)cx < (unsigned)Ww)
                 ? g[cy * Ww + cx]
                 : -1;
  }
  // ---- phase 2: issue all K/V gathers into registers (zero when invalid)
  const float* Kpb = Kp + ((size_t)dir * Bb + b) * Nn * Cc;
  const float* Vpb = Vp + ((size_t)dir * Bb + b) * Nn * Cc;
  float4 k4s[9], v4s[9];
#pragma unroll
  for (int l = 0; l < 9; l++) {
    float4 kk = make_float4(0.f, 0.f, 0.f, 0.f);
    float4 vv = make_float4(0.f, 0.f, 0.f, 0.f);
    int se = sel[l];
    if (se >= 0) {
      kk = *(const float4*)(Kpb + (size_t)se * Cc + c4 * 4);
      vv = *(const float4*)(Vpb + (size_t)se * Cc + c4 * 4);
    }
    k4s[l] = kk;
    v4s[l] = vv;
  }
  float4 qh4 =
      *(const float4*)(Qh + (((size_t)dir * Bb + b) * Nn + n) * Cc + c4 * 4);
  // invalid-slot score: qh . bk over the lane's head (reduce within 4 lanes)
  float4 bk4 = *(const float4*)(sbk + c4 * 4);
  float pb = qh4.x * bk4.x + qh4.y * bk4.y + qh4.z * bk4.z + qh4.w * bk4.w;
  pb += __shfl_xor(pb, 1);
  pb += __shfl_xor(pb, 2);
  // ---- phase 3: scores from registers (k4s=0 for invalid -> d=0 -> s=pb/4)
  float s[9];
#pragma unroll
  for (int l = 0; l < 9; l++) {
    float4 k4 = k4s[l];
    float d = qh4.x * k4.x + qh4.y * k4.y + qh4.z * k4.z + qh4.w * k4.w;
    d += __shfl_xor(d, 1);
    d += __shfl_xor(d, 2);  // lane's head dot
    s[l] = 0.25f * (pb + d);
  }
  // softmax over 9 slots for the lane's head
  float m = s[0];
#pragma unroll
  for (int l = 1; l < 9; l++) m = fmaxf(m, s[l]);
  float sum = 0.f;
#pragma unroll
  for (int l = 0; l < 9; l++) {
    s[l] = __expf(s[l] - m);
    sum += s[l];
  }
  // ---- phase 4: PV from registers (posv only for valid slots)
  float4 o4 = make_float4(0.f, 0.f, 0.f, 0.f);
#pragma unroll
  for (int l = 0; l < 9; l++) {
    float wp = (sel[l] >= 0) ? s[l] : 0.f;
    float4 v4 = v4s[l];
    float4 p4 = *(const float4*)(pv + l * Cc + c4 * 4);
    o4.x += wp * (v4.x + p4.x);
    o4.y += wp * (v4.y + p4.y);
    o4.z += wp * (v4.z + p4.z);
    o4.w += wp * (v4.w + p4.w);
  }
  float r = 1.f / sum;
  float4 bv4 = *(const float4*)(sbv + c4 * 4);
  o4 = make_float4(o4.x * r + bv4.x, o4.y * r + bv4.y, o4.z * r + bv4.z,
                   o4.w * r + bv4.w);
  // ---- output projection: lane computes out channels [4*c4, 4*c4+4)
  const float4* ow4 = (const float4*)ow;
  float4 sob4 = *(const float4*)(sob + c4 * 4);
  float acc0 = sob4.x, acc1 = sob4.y, acc2 = sob4.z, acc3 = sob4.w;
#pragma unroll
  for (int mm = 0; mm < 8; mm++) {
    float4 oj = shfl_xor4(o4, mm);  // o slice of group jb = c4 ^ mm
    int jb = c4 ^ mm;
    float4 w0 = ow4[(c4 * 4 + 0) * 8 + jb];
    float4 w1 = ow4[(c4 * 4 + 1) * 8 + jb];
    float4 w2 = ow4[(c4 * 4 + 2) * 8 + jb];
    float4 w3 = ow4[(c4 * 4 + 3) * 8 + jb];
    acc0 += oj.x * w0.x + oj.y * w0.y + oj.z * w0.z + oj.w * w0.w;
    acc1 += oj.x * w1.x + oj.y * w1.y + oj.z * w1.z + oj.w * w1.w;
    acc2 += oj.x * w2.x + oj.y * w2.y + oj.z * w2.z + oj.w * w2.w;
    acc3 += oj.x * w3.x + oj.y * w3.y + oj.z * w3.z + oj.w * w3.w;
  }
  *(float4*)(out_pts + (((size_t)dir * Bb + b) * Nn + n) * Cc + c4 * 4) =
      make_float4(acc0, acc1, acc2, acc3);
}

// Inverted scatter: grid pre-filled, no verify. One thread per canvas pixel;
// channel stores are wave-coalesced full lines.
__global__ __launch_bounds__(256) void scatter_k(
    const int* __restrict__ grids, const float* __restrict__ out_pts,
    float* __restrict__ out) {
  int db = blockIdx.y;
  int dir = db >> 2, b = db & 3;
  int p = blockIdx.x * 256 + threadIdx.x;
  const int* gq = grids + ((size_t)dir * Bb + b) * HWp;
  int se = gq[p];
  float* ob = out + (((size_t)dir * Bb + b) * Cc) * HWp + p;
  if (se < 0) {
#pragma unroll
    for (int c = 0; c < Cc; c++) ob[(size_t)c * HWp] = 0.f;
  } else {
    const float4* sp =
        (const float4*)(out_pts + (((size_t)dir * Bb + b) * Nn + se) * Cc);
#pragma unroll
    for (int c4 = 0; c4 < 8; c4++) {
      float4 v = sp[c4];
      ob[(size_t)(c4 * 4 + 0) * HWp] = v.x;
      ob[(size_t)(c4 * 4 + 1) * HWp] = v.y;
      ob[(size_t)(c4 * 4 + 2) * HWp] = v.z;
      ob[(size_t)(c4 * 4 + 3) * HWp] = v.w;
    }
  }
}

extern "C" void kernel_launch(void* const* d_in, const int* in_sizes, int n_in,
                              void* d_out, int out_size, void* d_ws, size_t ws_size,
                              hipStream_t stream) {
  const float* li_feats = (const float*)d_in[0];
  const int* li_coors = (const int*)d_in[1];
  const float* ra_feats = (const float*)d_in[2];
  const int* ra_coors = (const int*)d_in[3];
  const float* pos = (const float*)d_in[4];
  const float* in_w1 = (const float*)d_in[5];
  const float* in_b1 = (const float*)d_in[6];
  const float* out_w1 = (const float*)d_in[7];
  const float* out_b1 = (const float*)d_in[8];
  const float* in_w2 = (const float*)d_in[9];
  const float* in_b2 = (const float*)d_in[10];
  const float* out_w2 = (const float*)d_in[11];
  const float* out_b2 = (const float*)d_in[12];

  char* ws = (char*)d_ws;
  size_t off = 0;
  int* grids = (int*)(ws + off);
  off += (size_t)2 * Bb * HWp * 4;  // 3,276,800 B
  float* Qh = (float*)(ws + off);
  off += (size_t)2 * Bb * Nn * Cc * 4;  // 20,480,000 B
  float* Kp = (float*)(ws + off);
  off += (size_t)2 * Bb * Nn * Cc * 4;
  float* Vp = (float*)(ws + off);
  off += (size_t)2 * Bb * Nn * Cc * 4;
  float* out_pts = (float*)(ws + off);
  off += (size_t)2 * Bb * Nn * Cc * 4;
  float* posv = (float*)(ws + off);
  off += 2 * 9 * Cc * 4;  // total ~85.2 MB

  prep_k<<<803, 256, 0, stream>>>(grids, pos, in_w1, in_w2, posv);
  project_build_k<<<PROJ_TOTAL + BUILD_BLOCKS, 256, 0, stream>>>(
      li_feats, ra_feats, li_coors, ra_coors, in_w1, in_b1, in_w2, in_b2, Qh, Kp,
      Vp, grids);
  dim3 ga(Nn / 32, 2 * Bb);
  attn8_k<<<ga, 256, 0, stream>>>(li_coors, ra_coors, grids, Qh, Kp, Vp, posv,
                                  in_b1, in_b2, out_w1, out_b1, out_w2, out_b2,
                                  out_pts);
  dim3 gs(HWp / 256, 2 * Bb);
  scatter_k<<<gs, 256, 0, stream>>>(grids, out_pts, (float*)d_out);
}

// Round 15
// 91.766 us; speedup vs baseline: 1.1365x; 1.0303x over previous
//
#include <hip/hip_runtime.h>
#include <hip/hip_fp16.h>

constexpr int Hh = 320, Ww = 320, Cc = 32, Bb = 4, Nn = 20000;
constexpr int HWp = Hh * Ww;

__device__ __forceinline__ float4 shfl_xor4(float4 v, int m) {
  return make_float4(__shfl_xor(v.x, m), __shfl_xor(v.y, m),
                     __shfl_xor(v.z, m), __shfl_xor(v.w, m));
}

union H4 { __half2 h2[2]; float2 f2; };
union H8 { __half2 h2[4]; float4 f4; };

__device__ __forceinline__ void store_h4(__half* p, float4 v) {
  H4 u;
  u.h2[0] = __floats2half2_rn(v.x, v.y);
  u.h2[1] = __floats2half2_rn(v.z, v.w);
  *(float2*)p = u.f2;
}
__device__ __forceinline__ float4 cvt_h4(float2 raw) {
  H4 u;
  u.f2 = raw;
  float2 lo = __half22float2(u.h2[0]), hi = __half22float2(u.h2[1]);
  return make_float4(lo.x, lo.y, hi.x, hi.y);
}

// prep: blocks [0,800) fill grids with -1 (int4, full BW); blocks [800,803)
// compute posv[dir][l][c] = pos[l] @ wv_dir.T (fp32, tiny)
__global__ __launch_bounds__(256) void prep_k(
    int* __restrict__ grids, const float* __restrict__ pos,
    const float* __restrict__ in_w1, const float* __restrict__ in_w2,
    float* __restrict__ posv) {
  int bx = blockIdx.x;
  if (bx < 800) {
    int i = bx * 256 + threadIdx.x;  // 800*256 int4 = 2*4*HWp ints exactly
    ((int4*)grids)[i] = make_int4(-1, -1, -1, -1);
    return;
  }
  int t = (bx - 800) * 256 + threadIdx.x;
  if (t >= 2 * 9 * Cc) return;
  int dir = t / (9 * Cc);
  int rem = t - dir * 9 * Cc;
  int l = rem / Cc, ch = rem - l * Cc;
  const float* w = (dir == 0 ? in_w1 : in_w2) + (2 * Cc + ch) * Cc;
  const float* pl = pos + l * Cc;
  float acc = 0.f;
  for (int j = 0; j < Cc; j++) acc += pl[j] * w[j];
  posv[t] = acc;
}

// Fused: blocks [0, PROJ_TOTAL) = Q/K/V projection (register-tiled, 4 pts/thread,
// fp16 stores); blocks [PROJ_TOTAL, +BUILD_BLOCKS) = build_grid (grid pre-filled).
constexpr int PROJ_BLOCKS_PER_SB = 157;              // ceil(20000/128)
constexpr int PROJ_TOTAL = PROJ_BLOCKS_PER_SB * 8;   // 1256
constexpr int BUILD_BLOCKS = 625;                    // 160000/256 exact

__global__ __launch_bounds__(256) void project_build_k(
    const float* __restrict__ li_feats, const float* __restrict__ ra_feats,
    const int* __restrict__ li_coors, const int* __restrict__ ra_coors,
    const float* __restrict__ in_w1, const float* __restrict__ in_b1,
    const float* __restrict__ in_w2, const float* __restrict__ in_b2,
    __half* __restrict__ Qh, __half* __restrict__ Kp, __half* __restrict__ Vp,
    int* __restrict__ grids) {
  int bx = blockIdx.x;
  if (bx >= PROJ_TOTAL) {
    int idx = (bx - PROJ_TOTAL) * 256 + threadIdx.x;  // [0, 160000) exact
    int src = idx / (Bb * Nn);
    int r = idx - src * (Bb * Nn);
    int b = r / Nn, n = r - b * Nn;
    const int* c = (src == 0 ? li_coors : ra_coors) + ((size_t)b * Nn + n) * 2;
    grids[((size_t)src * Bb + b) * HWp + c[0] * Ww + c[1]] = n;
    return;
  }
  int sb = bx / PROJ_BLOCKS_PER_SB;
  int blk = bx - sb * PROJ_BLOCKS_PER_SB;
  int src = sb >> 2, b = sb & 3;
  // weights transposed, rows padded to 36 floats (9 float4) for bank spread
  __shared__ __align__(16) float wqT[32 * 36];
  __shared__ __align__(16) float wkT[32 * 36];
  __shared__ __align__(16) float wvT[32 * 36];
  __shared__ float bq[Cc];
  const float* wA = src == 0 ? in_w1 : in_w2;  // q weights: own direction
  const float* bA = src == 0 ? in_b1 : in_b2;
  const float* wB = src == 0 ? in_w2 : in_w1;  // k/v weights: other direction
  int t = threadIdx.x;
  for (int i = t; i < Cc * Cc; i += 256) {
    int c = i >> 5, j = i & 31;
    wqT[j * 36 + c] = wA[i];
    wkT[j * 36 + c] = wB[Cc * Cc + i];
    wvT[j * 36 + c] = wB[2 * Cc * Cc + i];
  }
  if (t < Cc) bq[t] = bA[t];
  __syncthreads();
  int quad = t >> 3, c4 = t & 7;
  int n0 = blk * 128 + quad * 4;
  if (n0 + 4 > Nn) n0 = Nn - 4;  // tail clamp: redundant idempotent work
  const float* f = (src == 0 ? li_feats : ra_feats) + ((size_t)b * Nn + n0) * Cc;
  const float4* wq4 = (const float4*)wqT;
  const float4* wk4 = (const float4*)wkT;
  const float4* wv4 = (const float4*)wvT;
  float4 bq4 = *(const float4*)(bq + c4 * 4);
  float4 aq[4], ak[4], av[4];
#pragma unroll
  for (int i = 0; i < 4; i++) {
    aq[i] = bq4;
    ak[i] = make_float4(0.f, 0.f, 0.f, 0.f);
    av[i] = make_float4(0.f, 0.f, 0.f, 0.f);
  }
#pragma unroll
  for (int j4 = 0; j4 < 8; j4++) {
    float fjs[4][4];
#pragma unroll
    for (int i = 0; i < 4; i++) {
      float4 v = ((const float4*)(f + i * Cc))[j4];
      fjs[i][0] = v.x; fjs[i][1] = v.y; fjs[i][2] = v.z; fjs[i][3] = v.w;
    }
#pragma unroll
    for (int u = 0; u < 4; u++) {
      int j = j4 * 4 + u;
      float4 q4 = wq4[j * 9 + c4];
      float4 k4 = wk4[j * 9 + c4];
      float4 v4 = wv4[j * 9 + c4];
#pragma unroll
      for (int i = 0; i < 4; i++) {
        float fj = fjs[i][u];
        aq[i].x += fj * q4.x; aq[i].y += fj * q4.y;
        aq[i].z += fj * q4.z; aq[i].w += fj * q4.w;
        ak[i].x += fj * k4.x; ak[i].y += fj * k4.y;
        ak[i].z += fj * k4.z; ak[i].w += fj * k4.w;
        av[i].x += fj * v4.x; av[i].y += fj * v4.y;
        av[i].z += fj * v4.z; av[i].w += fj * v4.w;
      }
    }
  }
  int dirkv = 1 - src;
  size_t qbase = (((size_t)src * Bb + b) * Nn + n0) * Cc + c4 * 4;
  size_t kvbase = (((size_t)dirkv * Bb + b) * Nn + n0) * Cc + c4 * 4;
#pragma unroll
  for (int i = 0; i < 4; i++) {
    store_h4(Qh + qbase + i * Cc, aq[i]);
    store_h4(Kp + kvbase + i * Cc, ak[i]);
    store_h4(Vp + kvbase + i * Cc, av[i]);
  }
}

// 8-lane-per-point attention + in-kernel output projection (r10-proven form,
// fp16 staging). All 9 sel loads 1-deep, then ALL 18 K/V gathers upfront into
// raw fp16 registers (half the bytes/VGPRs), converted at use.
__global__ __launch_bounds__(256) void attn8_k(
    const int* __restrict__ li_coors, const int* __restrict__ ra_coors,
    const int* __restrict__ grids, const __half* __restrict__ Qh,
    const __half* __restrict__ Kp, const __half* __restrict__ Vp,
    const float* __restrict__ posv, const float* __restrict__ in_b1,
    const float* __restrict__ in_b2, const float* __restrict__ out_w1,
    const float* __restrict__ out_b1, const float* __restrict__ out_w2,
    const float* __restrict__ out_b2, __half* __restrict__ out_pts) {
  int db = blockIdx.y;
  int dir = db >> 2, b = db & 3;
  __shared__ __align__(16) float ow[Cc * Cc];
  __shared__ __align__(16) float pv[9 * Cc];
  __shared__ float sbk[Cc], sbv[Cc], sob[Cc];
  const float* owp = dir == 0 ? out_w1 : out_w2;
  const float* obp = dir == 0 ? out_b1 : out_b2;
  const float* ibp = dir == 0 ? in_b1 : in_b2;
  int t = threadIdx.x;
  for (int i = t; i < Cc * Cc; i += 256) ow[i] = owp[i];
  for (int i = t; i < 9 * Cc; i += 256) pv[i] = posv[dir * 9 * Cc + i];
  if (t < Cc) {
    sbk[t] = ibp[Cc + t];
    sbv[t] = ibp[2 * Cc + t];
    sob[t] = obp[t];
  }
  __syncthreads();
  int pt = t >> 3, c4 = t & 7;
  int n = blockIdx.x * 32 + pt;  // 625*32 == 20000 exact, no tail
  const int2* qcp =
      (const int2*)((dir == 0 ? li_coors : ra_coors) + (size_t)b * Nn * 2);
  int2 yx = qcp[n];
  int y = yx.x, x = yx.y;
  const int* g = grids + ((size_t)(1 - dir) * Bb + b) * HWp;
  const int DY[9] = {0, -1, 1, 0, -1, 1, 0, -1, 1};
  const int DX[9] = {0, 0, 0, 1, 1, 1, -1, -1, -1};
  // ---- phase 1: all 9 sel loads (independent, 1-deep; grid pre-filled)
  int sel[9];
#pragma unroll
  for (int l = 0; l < 9; l++) {
    int cy = y + DY[l], cx = x + DX[l];
    sel[l] = ((unsigned)cy < (unsigned)Hh && (unsigned)cx < (unsigned)Ww)
                 ? g[cy * Ww + cx]
                 : -1;
  }
  // ---- phase 2: issue all K/V gathers (raw fp16, 8B/lane; zero if invalid)
  const __half* Kpb = Kp + ((size_t)dir * Bb + b) * Nn * Cc;
  const __half* Vpb = Vp + ((size_t)dir * Bb + b) * Nn * Cc;
  float2 kr[9], vr[9];
#pragma unroll
  for (int l = 0; l < 9; l++) {
    float2 kk = make_float2(0.f, 0.f);  // bit pattern 0 == fp16 zeros
    float2 vv = make_float2(0.f, 0.f);
    int se = sel[l];
    if (se >= 0) {
      kk = *(const float2*)(Kpb + (size_t)se * Cc + c4 * 4);
      vv = *(const float2*)(Vpb + (size_t)se * Cc + c4 * 4);
    }
    kr[l] = kk;
    vr[l] = vv;
  }
  float4 qh4 = cvt_h4(
      *(const float2*)(Qh + (((size_t)dir * Bb + b) * Nn + n) * Cc + c4 * 4));
  // invalid-slot score: qh . bk over the lane's head (reduce within 4 lanes)
  float4 bk4 = *(const float4*)(sbk + c4 * 4);
  float pb = qh4.x * bk4.x + qh4.y * bk4.y + qh4.z * bk4.z + qh4.w * bk4.w;
  pb += __shfl_xor(pb, 1);
  pb += __shfl_xor(pb, 2);
  // ---- phase 3: scores from registers (k=0 for invalid -> d=0 -> s=pb/4)
  float s[9];
#pragma unroll
  for (int l = 0; l < 9; l++) {
    float4 k4 = cvt_h4(kr[l]);
    float d = qh4.x * k4.x + qh4.y * k4.y + qh4.z * k4.z + qh4.w * k4.w;
    d += __shfl_xor(d, 1);
    d += __shfl_xor(d, 2);  // lane's head dot
    s[l] = 0.25f * (pb + d);
  }
  // softmax over 9 slots for the lane's head
  float m = s[0];
#pragma unroll
  for (int l = 1; l < 9; l++) m = fmaxf(m, s[l]);
  float sum = 0.f;
#pragma unroll
  for (int l = 0; l < 9; l++) {
    s[l] = __expf(s[l] - m);
    sum += s[l];
  }
  // ---- phase 4: PV from registers (posv only for valid slots)
  float4 o4 = make_float4(0.f, 0.f, 0.f, 0.f);
#pragma unroll
  for (int l = 0; l < 9; l++) {
    float wp = (sel[l] >= 0) ? s[l] : 0.f;
    float4 v4 = cvt_h4(vr[l]);
    float4 p4 = *(const float4*)(pv + l * Cc + c4 * 4);
    o4.x += wp * (v4.x + p4.x);
    o4.y += wp * (v4.y + p4.y);
    o4.z += wp * (v4.z + p4.z);
    o4.w += wp * (v4.w + p4.w);
  }
  float r = 1.f / sum;
  float4 bv4 = *(const float4*)(sbv + c4 * 4);
  o4 = make_float4(o4.x * r + bv4.x, o4.y * r + bv4.y, o4.z * r + bv4.z,
                   o4.w * r + bv4.w);
  // ---- output projection: lane computes out channels [4*c4, 4*c4+4)
  const float4* ow4 = (const float4*)ow;
  float4 sob4 = *(const float4*)(sob + c4 * 4);
  float acc0 = sob4.x, acc1 = sob4.y, acc2 = sob4.z, acc3 = sob4.w;
#pragma unroll
  for (int mm = 0; mm < 8; mm++) {
    float4 oj = shfl_xor4(o4, mm);  // o slice of group jb = c4 ^ mm
    int jb = c4 ^ mm;
    float4 w0 = ow4[(c4 * 4 + 0) * 8 + jb];
    float4 w1 = ow4[(c4 * 4 + 1) * 8 + jb];
    float4 w2 = ow4[(c4 * 4 + 2) * 8 + jb];
    float4 w3 = ow4[(c4 * 4 + 3) * 8 + jb];
    acc0 += oj.x * w0.x + oj.y * w0.y + oj.z * w0.z + oj.w * w0.w;
    acc1 += oj.x * w1.x + oj.y * w1.y + oj.z * w1.z + oj.w * w1.w;
    acc2 += oj.x * w2.x + oj.y * w2.y + oj.z * w2.z + oj.w * w2.w;
    acc3 += oj.x * w3.x + oj.y * w3.y + oj.z * w3.z + oj.w * w3.w;
  }
  store_h4(out_pts + (((size_t)dir * Bb + b) * Nn + n) * Cc + c4 * 4,
           make_float4(acc0, acc1, acc2, acc3));
}

// Inverted scatter: grid pre-filled. One thread per canvas pixel reads the
// point's 64B fp16 line, converts, writes fp32 channels (wave-coalesced).
__global__ __launch_bounds__(256) void scatter_k(
    const int* __restrict__ grids, const __half* __restrict__ out_pts,
    float* __restrict__ out) {
  int db = blockIdx.y;
  int dir = db >> 2, b = db & 3;
  int p = blockIdx.x * 256 + threadIdx.x;
  const int* gq = grids + ((size_t)dir * Bb + b) * HWp;
  int se = gq[p];
  float* ob = out + (((size_t)dir * Bb + b) * Cc) * HWp + p;
  if (se < 0) {
#pragma unroll
    for (int c = 0; c < Cc; c++) ob[(size_t)c * HWp] = 0.f;
  } else {
    const float4* sp =
        (const float4*)(out_pts + (((size_t)dir * Bb + b) * Nn + se) * Cc);
#pragma unroll
    for (int c8 = 0; c8 < 4; c8++) {
      H8 u;
      u.f4 = sp[c8];
#pragma unroll
      for (int k = 0; k < 4; k++) {
        float2 pr = __half22float2(u.h2[k]);
        ob[(size_t)(c8 * 8 + k * 2 + 0) * HWp] = pr.x;
        ob[(size_t)(c8 * 8 + k * 2 + 1) * HWp] = pr.y;
      }
    }
  }
}

extern "C" void kernel_launch(void* const* d_in, const int* in_sizes, int n_in,
                              void* d_out, int out_size, void* d_ws, size_t ws_size,
                              hipStream_t stream) {
  const float* li_feats = (const float*)d_in[0];
  const int* li_coors = (const int*)d_in[1];
  const float* ra_feats = (const float*)d_in[2];
  const int* ra_coors = (const int*)d_in[3];
  const float* pos = (const float*)d_in[4];
  const float* in_w1 = (const float*)d_in[5];
  const float* in_b1 = (const float*)d_in[6];
  const float* out_w1 = (const float*)d_in[7];
  const float* out_b1 = (const float*)d_in[8];
  const float* in_w2 = (const float*)d_in[9];
  const float* in_b2 = (const float*)d_in[10];
  const float* out_w2 = (const float*)d_in[11];
  const float* out_b2 = (const float*)d_in[12];

  char* ws = (char*)d_ws;
  size_t off = 0;
  int* grids = (int*)(ws + off);
  off += (size_t)2 * Bb * HWp * 4;  // 3,276,800 B
  __half* Qh = (__half*)(ws + off);
  off += (size_t)2 * Bb * Nn * Cc * 2;  // 10,240,000 B
  __half* Kp = (__half*)(ws + off);
  off += (size_t)2 * Bb * Nn * Cc * 2;
  __half* Vp = (__half*)(ws + off);
  off += (size_t)2 * Bb * Nn * Cc * 2;
  __half* out_pts = (__half*)(ws + off);
  off += (size_t)2 * Bb * Nn * Cc * 2;
  float* posv = (float*)(ws + off);
  off += 2 * 9 * Cc * 4;  // total ~44.3 MB

  prep_k<<<803, 256, 0, stream>>>(grids, pos, in_w1, in_w2, posv);
  project_build_k<<<PROJ_TOTAL + BUILD_BLOCKS, 256, 0, stream>>>(
      li_feats, ra_feats, li_coors, ra_coors, in_w1, in_b1, in_w2, in_b2, Qh, Kp,
      Vp, grids);
  dim3 ga(Nn / 32, 2 * Bb);
  attn8_k<<<ga, 256, 0, stream>>>(li_coors, ra_coors, grids, Qh, Kp, Vp, posv,
                                  in_b1, in_b2, out_w1, out_b1, out_w2, out_b2,
                                  out_pts);
  dim3 gs(HWp / 256, 2 * Bb);
  scatter_k<<<gs, 256, 0, stream>>>(grids, out_pts, (float*)d_out);
}

// Round 16
// 89.023 us; speedup vs baseline: 1.1715x; 1.0308x over previous
//
#include <hip/hip_runtime.h>
#include <hip/hip_fp16.h>

constexpr int Hh = 320, Ww = 320, Cc = 32, Bb = 4, Nn = 20000;
constexpr int HWp = Hh * Ww;

__device__ __forceinline__ float4 shfl_xor4(float4 v, int m) {
  return make_float4(__shfl_xor(v.x, m), __shfl_xor(v.y, m),
                     __shfl_xor(v.z, m), __shfl_xor(v.w, m));
}

// DPP quad_perm helpers (VALU lane exchange within 4-lane quads; no DS pipe).
// quad_perm [a,b,c,d] ctrl = a|(b<<2)|(c<<4)|(d<<6): xor1=0xB1 xor2=0x4E xor3=0x1B
template <int CTRL>
__device__ __forceinline__ float dpp_mov(float x) {
  return __int_as_float(
      __builtin_amdgcn_update_dpp(0, __float_as_int(x), CTRL, 0xF, 0xF, true));
}
template <int CTRL>
__device__ __forceinline__ float4 dpp_mov4(float4 v) {
  return make_float4(dpp_mov<CTRL>(v.x), dpp_mov<CTRL>(v.y),
                     dpp_mov<CTRL>(v.z), dpp_mov<CTRL>(v.w));
}
__device__ __forceinline__ float quad_add_xor1(float x) {
  return x + dpp_mov<0xB1>(x);
}
__device__ __forceinline__ float quad_add_xor2(float x) {
  return x + dpp_mov<0x4E>(x);
}

union H4 { __half2 h2[2]; float2 f2; };
union H8 { __half2 h2[4]; float4 f4; };

__device__ __forceinline__ void store_h4(__half* p, float4 v) {
  H4 u;
  u.h2[0] = __floats2half2_rn(v.x, v.y);
  u.h2[1] = __floats2half2_rn(v.z, v.w);
  *(float2*)p = u.f2;
}
__device__ __forceinline__ float4 cvt_h4(float2 raw) {
  H4 u;
  u.f2 = raw;
  float2 lo = __half22float2(u.h2[0]), hi = __half22float2(u.h2[1]);
  return make_float4(lo.x, lo.y, hi.x, hi.y);
}

// prep: blocks [0,800) fill grids with -1 (int4, full BW); blocks [800,803)
// compute posv[dir][l][c] = pos[l] @ wv_dir.T (fp32, tiny)
__global__ __launch_bounds__(256) void prep_k(
    int* __restrict__ grids, const float* __restrict__ pos,
    const float* __restrict__ in_w1, const float* __restrict__ in_w2,
    float* __restrict__ posv) {
  int bx = blockIdx.x;
  if (bx < 800) {
    int i = bx * 256 + threadIdx.x;  // 800*256 int4 = 2*4*HWp ints exactly
    ((int4*)grids)[i] = make_int4(-1, -1, -1, -1);
    return;
  }
  int t = (bx - 800) * 256 + threadIdx.x;
  if (t >= 2 * 9 * Cc) return;
  int dir = t / (9 * Cc);
  int rem = t - dir * 9 * Cc;
  int l = rem / Cc, ch = rem - l * Cc;
  const float* w = (dir == 0 ? in_w1 : in_w2) + (2 * Cc + ch) * Cc;
  const float* pl = pos + l * Cc;
  float acc = 0.f;
  for (int j = 0; j < Cc; j++) acc += pl[j] * w[j];
  posv[t] = acc;
}

// Fused: blocks [0, PROJ_TOTAL) = Q/K/V projection (register-tiled, 4 pts/thread,
// fp16 stores); blocks [PROJ_TOTAL, +BUILD_BLOCKS) = build_grid (grid pre-filled).
constexpr int PROJ_BLOCKS_PER_SB = 157;              // ceil(20000/128)
constexpr int PROJ_TOTAL = PROJ_BLOCKS_PER_SB * 8;   // 1256
constexpr int BUILD_BLOCKS = 625;                    // 160000/256 exact

__global__ __launch_bounds__(256) void project_build_k(
    const float* __restrict__ li_feats, const float* __restrict__ ra_feats,
    const int* __restrict__ li_coors, const int* __restrict__ ra_coors,
    const float* __restrict__ in_w1, const float* __restrict__ in_b1,
    const float* __restrict__ in_w2, const float* __restrict__ in_b2,
    __half* __restrict__ Qh, __half* __restrict__ Kp, __half* __restrict__ Vp,
    int* __restrict__ grids) {
  int bx = blockIdx.x;
  if (bx >= PROJ_TOTAL) {
    int idx = (bx - PROJ_TOTAL) * 256 + threadIdx.x;  // [0, 160000) exact
    int src = idx / (Bb * Nn);
    int r = idx - src * (Bb * Nn);
    int b = r / Nn, n = r - b * Nn;
    const int* c = (src == 0 ? li_coors : ra_coors) + ((size_t)b * Nn + n) * 2;
    grids[((size_t)src * Bb + b) * HWp + c[0] * Ww + c[1]] = n;
    return;
  }
  int sb = bx / PROJ_BLOCKS_PER_SB;
  int blk = bx - sb * PROJ_BLOCKS_PER_SB;
  int src = sb >> 2, b = sb & 3;
  // weights transposed, rows padded to 36 floats (9 float4) for bank spread
  __shared__ __align__(16) float wqT[32 * 36];
  __shared__ __align__(16) float wkT[32 * 36];
  __shared__ __align__(16) float wvT[32 * 36];
  __shared__ float bq[Cc];
  const float* wA = src == 0 ? in_w1 : in_w2;  // q weights: own direction
  const float* bA = src == 0 ? in_b1 : in_b2;
  const float* wB = src == 0 ? in_w2 : in_w1;  // k/v weights: other direction
  int t = threadIdx.x;
  for (int i = t; i < Cc * Cc; i += 256) {
    int c = i >> 5, j = i & 31;
    wqT[j * 36 + c] = wA[i];
    wkT[j * 36 + c] = wB[Cc * Cc + i];
    wvT[j * 36 + c] = wB[2 * Cc * Cc + i];
  }
  if (t < Cc) bq[t] = bA[t];
  __syncthreads();
  int quad = t >> 3, c4 = t & 7;
  int n0 = blk * 128 + quad * 4;
  if (n0 + 4 > Nn) n0 = Nn - 4;  // tail clamp: redundant idempotent work
  const float* f = (src == 0 ? li_feats : ra_feats) + ((size_t)b * Nn + n0) * Cc;
  const float4* wq4 = (const float4*)wqT;
  const float4* wk4 = (const float4*)wkT;
  const float4* wv4 = (const float4*)wvT;
  float4 bq4 = *(const float4*)(bq + c4 * 4);
  float4 aq[4], ak[4], av[4];
#pragma unroll
  for (int i = 0; i < 4; i++) {
    aq[i] = bq4;
    ak[i] = make_float4(0.f, 0.f, 0.f, 0.f);
    av[i] = make_float4(0.f, 0.f, 0.f, 0.f);
  }
#pragma unroll
  for (int j4 = 0; j4 < 8; j4++) {
    float fjs[4][4];
#pragma unroll
    for (int i = 0; i < 4; i++) {
      float4 v = ((const float4*)(f + i * Cc))[j4];
      fjs[i][0] = v.x; fjs[i][1] = v.y; fjs[i][2] = v.z; fjs[i][3] = v.w;
    }
#pragma unroll
    for (int u = 0; u < 4; u++) {
      int j = j4 * 4 + u;
      float4 q4 = wq4[j * 9 + c4];
      float4 k4 = wk4[j * 9 + c4];
      float4 v4 = wv4[j * 9 + c4];
#pragma unroll
      for (int i = 0; i < 4; i++) {
        float fj = fjs[i][u];
        aq[i].x += fj * q4.x; aq[i].y += fj * q4.y;
        aq[i].z += fj * q4.z; aq[i].w += fj * q4.w;
        ak[i].x += fj * k4.x; ak[i].y += fj * k4.y;
        ak[i].z += fj * k4.z; ak[i].w += fj * k4.w;
        av[i].x += fj * v4.x; av[i].y += fj * v4.y;
        av[i].z += fj * v4.z; av[i].w += fj * v4.w;
      }
    }
  }
  int dirkv = 1 - src;
  size_t qbase = (((size_t)src * Bb + b) * Nn + n0) * Cc + c4 * 4;
  size_t kvbase = (((size_t)dirkv * Bb + b) * Nn + n0) * Cc + c4 * 4;
#pragma unroll
  for (int i = 0; i < 4; i++) {
    store_h4(Qh + qbase + i * Cc, aq[i]);
    store_h4(Kp + kvbase + i * Cc, ak[i]);
    store_h4(Vp + kvbase + i * Cc, av[i]);
  }
}

// 8-lane-per-point attention + in-kernel output projection (r15 base).
// DS-pipe-minimized: head reductions via DPP quad adds; out-proj rotations via
// DPP quad_perm (xor1/2/3) + a single xor4 shuffle. ow reads stay in LDS
// (broadcast-friendly). All 18 K/V gathers upfront into raw fp16 registers.
__global__ __launch_bounds__(256) void attn8_k(
    const int* __restrict__ li_coors, const int* __restrict__ ra_coors,
    const int* __restrict__ grids, const __half* __restrict__ Qh,
    const __half* __restrict__ Kp, const __half* __restrict__ Vp,
    const float* __restrict__ posv, const float* __restrict__ in_b1,
    const float* __restrict__ in_b2, const float* __restrict__ out_w1,
    const float* __restrict__ out_b1, const float* __restrict__ out_w2,
    const float* __restrict__ out_b2, __half* __restrict__ out_pts) {
  int db = blockIdx.y;
  int dir = db >> 2, b = db & 3;
  __shared__ __align__(16) float ow[Cc * Cc];
  __shared__ __align__(16) float pv[9 * Cc];
  __shared__ float sbk[Cc], sbv[Cc], sob[Cc];
  const float* owp = dir == 0 ? out_w1 : out_w2;
  const float* obp = dir == 0 ? out_b1 : out_b2;
  const float* ibp = dir == 0 ? in_b1 : in_b2;
  int t = threadIdx.x;
  for (int i = t; i < Cc * Cc; i += 256) ow[i] = owp[i];
  for (int i = t; i < 9 * Cc; i += 256) pv[i] = posv[dir * 9 * Cc + i];
  if (t < Cc) {
    sbk[t] = ibp[Cc + t];
    sbv[t] = ibp[2 * Cc + t];
    sob[t] = obp[t];
  }
  __syncthreads();
  int pt = t >> 3, c4 = t & 7;
  int n = blockIdx.x * 32 + pt;  // 625*32 == 20000 exact, no tail
  const int2* qcp =
      (const int2*)((dir == 0 ? li_coors : ra_coors) + (size_t)b * Nn * 2);
  int2 yx = qcp[n];
  int y = yx.x, x = yx.y;
  const int* g = grids + ((size_t)(1 - dir) * Bb + b) * HWp;
  const int DY[9] = {0, -1, 1, 0, -1, 1, 0, -1, 1};
  const int DX[9] = {0, 0, 0, 1, 1, 1, -1, -1, -1};
  // ---- phase 1: all 9 sel loads (independent, 1-deep; grid pre-filled)
  int sel[9];
#pragma unroll
  for (int l = 0; l < 9; l++) {
    int cy = y + DY[l], cx = x + DX[l];
    sel[l] = ((unsigned)cy < (unsigned)Hh && (unsigned)cx < (unsigned)Ww)
                 ? g[cy * Ww + cx]
                 : -1;
  }
  // ---- phase 2: issue all K/V gathers (raw fp16, 8B/lane; zero if invalid)
  const __half* Kpb = Kp + ((size_t)dir * Bb + b) * Nn * Cc;
  const __half* Vpb = Vp + ((size_t)dir * Bb + b) * Nn * Cc;
  float2 kr[9], vr[9];
#pragma unroll
  for (int l = 0; l < 9; l++) {
    float2 kk = make_float2(0.f, 0.f);  // bit pattern 0 == fp16 zeros
    float2 vv = make_float2(0.f, 0.f);
    int se = sel[l];
    if (se >= 0) {
      kk = *(const float2*)(Kpb + (size_t)se * Cc + c4 * 4);
      vv = *(const float2*)(Vpb + (size_t)se * Cc + c4 * 4);
    }
    kr[l] = kk;
    vr[l] = vv;
  }
  float4 qh4 = cvt_h4(
      *(const float2*)(Qh + (((size_t)dir * Bb + b) * Nn + n) * Cc + c4 * 4));
  // invalid-slot score: qh . bk over the lane's head (DPP quad reduce)
  float4 bk4 = *(const float4*)(sbk + c4 * 4);
  float pb = qh4.x * bk4.x + qh4.y * bk4.y + qh4.z * bk4.z + qh4.w * bk4.w;
  pb = quad_add_xor1(pb);
  pb = quad_add_xor2(pb);
  // ---- phase 3: scores from registers (k=0 for invalid -> d=0 -> s=pb/4)
  float s[9];
#pragma unroll
  for (int l = 0; l < 9; l++) {
    float4 k4 = cvt_h4(kr[l]);
    float d = qh4.x * k4.x + qh4.y * k4.y + qh4.z * k4.z + qh4.w * k4.w;
    d = quad_add_xor1(d);
    d = quad_add_xor2(d);  // lane's head dot
    s[l] = 0.25f * (pb + d);
  }
  // softmax over 9 slots for the lane's head
  float m = s[0];
#pragma unroll
  for (int l = 1; l < 9; l++) m = fmaxf(m, s[l]);
  float sum = 0.f;
#pragma unroll
  for (int l = 0; l < 9; l++) {
    s[l] = __expf(s[l] - m);
    sum += s[l];
  }
  // ---- phase 4: PV from registers (posv only for valid slots)
  float4 o4 = make_float4(0.f, 0.f, 0.f, 0.f);
#pragma unroll
  for (int l = 0; l < 9; l++) {
    float wp = (sel[l] >= 0) ? s[l] : 0.f;
    float4 v4 = cvt_h4(vr[l]);
    float4 p4 = *(const float4*)(pv + l * Cc + c4 * 4);
    o4.x += wp * (v4.x + p4.x);
    o4.y += wp * (v4.y + p4.y);
    o4.z += wp * (v4.z + p4.z);
    o4.w += wp * (v4.w + p4.w);
  }
  float r = 1.f / sum;
  float4 bv4 = *(const float4*)(sbv + c4 * 4);
  o4 = make_float4(o4.x * r + bv4.x, o4.y * r + bv4.y, o4.z * r + bv4.z,
                   o4.w * r + bv4.w);
  // ---- output projection: lane computes out channels [4*c4, 4*c4+4).
  // o-slice exchange: xor1/2/3 via DPP quad_perm (VALU); xor4 via one shuffle.
  const float4* ow4 = (const float4*)ow;
  float4 sob4 = *(const float4*)(sob + c4 * 4);
  float acc0 = sob4.x, acc1 = sob4.y, acc2 = sob4.z, acc3 = sob4.w;
#define OUTPROJ_ACC(OJ, JB)                                            \
  {                                                                    \
    float4 oj = (OJ);                                                  \
    int jb = (JB);                                                     \
    float4 w0 = ow4[(c4 * 4 + 0) * 8 + jb];                            \
    float4 w1 = ow4[(c4 * 4 + 1) * 8 + jb];                            \
    float4 w2 = ow4[(c4 * 4 + 2) * 8 + jb];                            \
    float4 w3 = ow4[(c4 * 4 + 3) * 8 + jb];                            \
    acc0 += oj.x * w0.x + oj.y * w0.y + oj.z * w0.z + oj.w * w0.w;     \
    acc1 += oj.x * w1.x + oj.y * w1.y + oj.z * w1.z + oj.w * w1.w;     \
    acc2 += oj.x * w2.x + oj.y * w2.y + oj.z * w2.z + oj.w * w2.w;     \
    acc3 += oj.x * w3.x + oj.y * w3.y + oj.z * w3.z + oj.w * w3.w;     \
  }
  OUTPROJ_ACC(o4, c4);
  OUTPROJ_ACC(dpp_mov4<0xB1>(o4), c4 ^ 1);
  OUTPROJ_ACC(dpp_mov4<0x4E>(o4), c4 ^ 2);
  OUTPROJ_ACC(dpp_mov4<0x1B>(o4), c4 ^ 3);
  float4 o4s = shfl_xor4(o4, 4);  // slice of group c4^4
  OUTPROJ_ACC(o4s, c4 ^ 4);
  OUTPROJ_ACC(dpp_mov4<0xB1>(o4s), c4 ^ 5);
  OUTPROJ_ACC(dpp_mov4<0x4E>(o4s), c4 ^ 6);
  OUTPROJ_ACC(dpp_mov4<0x1B>(o4s), c4 ^ 7);
#undef OUTPROJ_ACC
  store_h4(out_pts + (((size_t)dir * Bb + b) * Nn + n) * Cc + c4 * 4,
           make_float4(acc0, acc1, acc2, acc3));
}

// Inverted scatter: grid pre-filled. One thread per canvas pixel reads the
// point's 64B fp16 line, converts, writes fp32 channels (wave-coalesced).
__global__ __launch_bounds__(256) void scatter_k(
    const int* __restrict__ grids, const __half* __restrict__ out_pts,
    float* __restrict__ out) {
  int db = blockIdx.y;
  int dir = db >> 2, b = db & 3;
  int p = blockIdx.x * 256 + threadIdx.x;
  const int* gq = grids + ((size_t)dir * Bb + b) * HWp;
  int se = gq[p];
  float* ob = out + (((size_t)dir * Bb + b) * Cc) * HWp + p;
  if (se < 0) {
#pragma unroll
    for (int c = 0; c < Cc; c++) ob[(size_t)c * HWp] = 0.f;
  } else {
    const float4* sp =
        (const float4*)(out_pts + (((size_t)dir * Bb + b) * Nn + se) * Cc);
#pragma unroll
    for (int c8 = 0; c8 < 4; c8++) {
      H8 u;
      u.f4 = sp[c8];
#pragma unroll
      for (int k = 0; k < 4; k++) {
        float2 pr = __half22float2(u.h2[k]);
        ob[(size_t)(c8 * 8 + k * 2 + 0) * HWp] = pr.x;
        ob[(size_t)(c8 * 8 + k * 2 + 1) * HWp] = pr.y;
      }
    }
  }
}

extern "C" void kernel_launch(void* const* d_in, const int* in_sizes, int n_in,
                              void* d_out, int out_size, void* d_ws, size_t ws_size,
                              hipStream_t stream) {
  const float* li_feats = (const float*)d_in[0];
  const int* li_coors = (const int*)d_in[1];
  const float* ra_feats = (const float*)d_in[2];
  const int* ra_coors = (const int*)d_in[3];
  const float* pos = (const float*)d_in[4];
  const float* in_w1 = (const float*)d_in[5];
  const float* in_b1 = (const float*)d_in[6];
  const float* out_w1 = (const float*)d_in[7];
  const float* out_b1 = (const float*)d_in[8];
  const float* in_w2 = (const float*)d_in[9];
  const float* in_b2 = (const float*)d_in[10];
  const float* out_w2 = (const float*)d_in[11];
  const float* out_b2 = (const float*)d_in[12];

  char* ws = (char*)d_ws;
  size_t off = 0;
  int* grids = (int*)(ws + off);
  off += (size_t)2 * Bb * HWp * 4;  // 3,276,800 B
  __half* Qh = (__half*)(ws + off);
  off += (size_t)2 * Bb * Nn * Cc * 2;  // 10,240,000 B
  __half* Kp = (__half*)(ws + off);
  off += (size_t)2 * Bb * Nn * Cc * 2;
  __half* Vp = (__half*)(ws + off);
  off += (size_t)2 * Bb * Nn * Cc * 2;
  __half* out_pts = (__half*)(ws + off);
  off += (size_t)2 * Bb * Nn * Cc * 2;
  float* posv = (float*)(ws + off);
  off += 2 * 9 * Cc * 4;  // total ~44.3 MB

  prep_k<<<803, 256, 0, stream>>>(grids, pos, in_w1, in_w2, posv);
  project_build_k<<<PROJ_TOTAL + BUILD_BLOCKS, 256, 0, stream>>>(
      li_feats, ra_feats, li_coors, ra_coors, in_w1, in_b1, in_w2, in_b2, Qh, Kp,
      Vp, grids);
  dim3 ga(Nn / 32, 2 * Bb);
  attn8_k<<<ga, 256, 0, stream>>>(li_coors, ra_coors, grids, Qh, Kp, Vp, posv,
                                  in_b1, in_b2, out_w1, out_b1, out_w2, out_b2,
                                  out_pts);
  dim3 gs(HWp / 256, 2 * Bb);
  scatter_k<<<gs, 256, 0, stream>>>(grids, out_pts, (float*)d_out);
}

// Round 17
// 88.770 us; speedup vs baseline: 1.1748x; 1.0029x over previous
//
#include <hip/hip_runtime.h>
#include <hip/hip_fp16.h>

constexpr int Hh = 320, Ww = 320, Cc = 32, Bb = 4, Nn = 20000;
constexpr int HWp = Hh * Ww;

// DPP quad_perm helpers (VALU lane exchange within 4-lane quads; no DS pipe).
template <int CTRL>
__device__ __forceinline__ float dpp_mov(float x) {
  return __int_as_float(
      __builtin_amdgcn_update_dpp(0, __float_as_int(x), CTRL, 0xF, 0xF, true));
}
__device__ __forceinline__ float quad_add_xor1(float x) {
  return x + dpp_mov<0xB1>(x);
}
__device__ __forceinline__ float quad_add_xor2(float x) {
  return x + dpp_mov<0x4E>(x);
}

union H4 { __half2 h2[2]; float2 f2; };
union H8 { __half2 h2[4]; float4 f4; };

__device__ __forceinline__ void store_h4(__half* p, float4 v) {
  H4 u;
  u.h2[0] = __floats2half2_rn(v.x, v.y);
  u.h2[1] = __floats2half2_rn(v.z, v.w);
  *(float2*)p = u.f2;
}
__device__ __forceinline__ float4 cvt_h4(float2 raw) {
  H4 u;
  u.f2 = raw;
  float2 lo = __half22float2(u.h2[0]), hi = __half22float2(u.h2[1]);
  return make_float4(lo.x, lo.y, hi.x, hi.y);
}

// prep: blocks [0,800) fill grids with -1; blocks 800/801: per-dir fold
// constants. Wvo_h = ow[:,16h:16h+16] @ wv[16h:16h+16,:] (PER-HEAD fold of the
// output projection into V -- valid because each head has its own softmax).
// pv2[h][l][c] = pos_l @ Wvo_h.T ; obias2[c] = out_b[c] + sum_j bv[j]*ow[c,j].
__global__ __launch_bounds__(256) void prep_k(
    int* __restrict__ grids, const float* __restrict__ pos,
    const float* __restrict__ in_w1, const float* __restrict__ in_b1,
    const float* __restrict__ out_w1, const float* __restrict__ out_b1,
    const float* __restrict__ in_w2, const float* __restrict__ in_b2,
    const float* __restrict__ out_w2, const float* __restrict__ out_b2,
    float* __restrict__ Wvo, float* __restrict__ pv2g,
    float* __restrict__ obias2) {
  int bx = blockIdx.x;
  if (bx < 800) {
    int i = bx * 256 + threadIdx.x;  // 800*256 int4 = 2*4*HWp ints exactly
    ((int4*)grids)[i] = make_int4(-1, -1, -1, -1);
    return;
  }
  int dir = bx - 800;
  const float* iw = dir == 0 ? in_w1 : in_w2;
  const float* ib = dir == 0 ? in_b1 : in_b2;
  const float* owp = dir == 0 ? out_w1 : out_w2;
  const float* obp = dir == 0 ? out_b1 : out_b2;
  __shared__ float sow[1024], swv[1024], sW[2048];
  int t = threadIdx.x;
  for (int i = t; i < 1024; i += 256) {
    sow[i] = owp[i];
    swv[i] = iw[2 * Cc * Cc + i];  // wv rows of in_w
  }
  __syncthreads();
  for (int e = t; e < 2048; e += 256) {
    int h = e >> 10, idx = e & 1023;
    int c = idx >> 5, j = idx & 31;
    float acc = 0.f;
    for (int jj = 0; jj < 16; jj++)
      acc += sow[c * 32 + h * 16 + jj] * swv[(h * 16 + jj) * 32 + j];
    sW[e] = acc;
    Wvo[dir * 2048 + e] = acc;
  }
  __syncthreads();
  for (int e = t; e < 576; e += 256) {  // 2 heads x 9 slots x 32 ch
    int h = e / 288, rem = e - h * 288;
    int l = rem >> 5, c = rem & 31;
    float acc = 0.f;
    for (int j = 0; j < 32; j++) acc += pos[l * 32 + j] * sW[h * 1024 + c * 32 + j];
    pv2g[dir * 576 + e] = acc;
  }
  if (t < Cc) {
    float acc = obp[t];
    for (int j = 0; j < 32; j++) acc += ib[2 * Cc + j] * sow[t * 32 + j];
    obias2[dir * Cc + t] = acc;
  }
}

// Fused: blocks [0, PROJ_TOTAL) = Q/K/V0f/V1f projection (4 pts/thread, fp16
// stores; V0f/V1f are the per-head folded V); rest = build_grid (pre-filled).
constexpr int PROJ_BLOCKS_PER_SB = 157;              // ceil(20000/128)
constexpr int PROJ_TOTAL = PROJ_BLOCKS_PER_SB * 8;   // 1256
constexpr int BUILD_BLOCKS = 625;                    // 160000/256 exact

__global__ __launch_bounds__(256) void project_build_k(
    const float* __restrict__ li_feats, const float* __restrict__ ra_feats,
    const int* __restrict__ li_coors, const int* __restrict__ ra_coors,
    const float* __restrict__ in_w1, const float* __restrict__ in_b1,
    const float* __restrict__ in_w2, const float* __restrict__ in_b2,
    const float* __restrict__ Wvo,
    __half* __restrict__ Qh, __half* __restrict__ Kp,
    __half* __restrict__ V0, __half* __restrict__ V1,
    int* __restrict__ grids) {
  int bx = blockIdx.x;
  if (bx >= PROJ_TOTAL) {
    int idx = (bx - PROJ_TOTAL) * 256 + threadIdx.x;  // [0, 160000) exact
    int src = idx / (Bb * Nn);
    int r = idx - src * (Bb * Nn);
    int b = r / Nn, n = r - b * Nn;
    const int* c = (src == 0 ? li_coors : ra_coors) + ((size_t)b * Nn + n) * 2;
    grids[((size_t)src * Bb + b) * HWp + c[0] * Ww + c[1]] = n;
    return;
  }
  int sb = bx / PROJ_BLOCKS_PER_SB;
  int blk = bx - sb * PROJ_BLOCKS_PER_SB;
  int src = sb >> 2, b = sb & 3;
  // weights transposed, rows padded to 36 floats (9 float4) for bank spread
  __shared__ __align__(16) float wqT[32 * 36];
  __shared__ __align__(16) float wkT[32 * 36];
  __shared__ __align__(16) float w0T[32 * 36];
  __shared__ __align__(16) float w1T[32 * 36];
  __shared__ float bq[Cc];
  const float* wA = src == 0 ? in_w1 : in_w2;  // q weights: own direction
  const float* bA = src == 0 ? in_b1 : in_b2;
  const float* wB = src == 0 ? in_w2 : in_w1;  // k weights: other direction
  int dirkv = 1 - src;
  const float* Wf = Wvo + (size_t)dirkv * 2048;  // per-head folded V weights
  int t = threadIdx.x;
  for (int i = t; i < Cc * Cc; i += 256) {
    int c = i >> 5, j = i & 31;
    wqT[j * 36 + c] = wA[i];
    wkT[j * 36 + c] = wB[Cc * Cc + i];
    w0T[j * 36 + c] = Wf[i];
    w1T[j * 36 + c] = Wf[1024 + i];
  }
  if (t < Cc) bq[t] = bA[t];
  __syncthreads();
  int quad = t >> 3, c4 = t & 7;
  int n0 = blk * 128 + quad * 4;
  if (n0 + 4 > Nn) n0 = Nn - 4;  // tail clamp: redundant idempotent work
  const float* f = (src == 0 ? li_feats : ra_feats) + ((size_t)b * Nn + n0) * Cc;
  const float4* wq4 = (const float4*)wqT;
  const float4* wk4 = (const float4*)wkT;
  const float4* w04 = (const float4*)w0T;
  const float4* w14 = (const float4*)w1T;
  float4 bq4 = *(const float4*)(bq + c4 * 4);
  float4 aq[4], ak[4], a0[4], a1[4];
#pragma unroll
  for (int i = 0; i < 4; i++) {
    aq[i] = bq4;
    ak[i] = make_float4(0.f, 0.f, 0.f, 0.f);
    a0[i] = make_float4(0.f, 0.f, 0.f, 0.f);
    a1[i] = make_float4(0.f, 0.f, 0.f, 0.f);
  }
#pragma unroll
  for (int j4 = 0; j4 < 8; j4++) {
    float fjs[4][4];
#pragma unroll
    for (int i = 0; i < 4; i++) {
      float4 v = ((const float4*)(f + i * Cc))[j4];
      fjs[i][0] = v.x; fjs[i][1] = v.y; fjs[i][2] = v.z; fjs[i][3] = v.w;
    }
#pragma unroll
    for (int u = 0; u < 4; u++) {
      int j = j4 * 4 + u;
      float4 q4 = wq4[j * 9 + c4];
      float4 k4 = wk4[j * 9 + c4];
      float4 v04 = w04[j * 9 + c4];
      float4 v14 = w14[j * 9 + c4];
#pragma unroll
      for (int i = 0; i < 4; i++) {
        float fj = fjs[i][u];
        aq[i].x += fj * q4.x; aq[i].y += fj * q4.y;
        aq[i].z += fj * q4.z; aq[i].w += fj * q4.w;
        ak[i].x += fj * k4.x; ak[i].y += fj * k4.y;
        ak[i].z += fj * k4.z; ak[i].w += fj * k4.w;
        a0[i].x += fj * v04.x; a0[i].y += fj * v04.y;
        a0[i].z += fj * v04.z; a0[i].w += fj * v04.w;
        a1[i].x += fj * v14.x; a1[i].y += fj * v14.y;
        a1[i].z += fj * v14.z; a1[i].w += fj * v14.w;
      }
    }
  }
  size_t qbase = (((size_t)src * Bb + b) * Nn + n0) * Cc + c4 * 4;
  size_t kvbase = (((size_t)dirkv * Bb + b) * Nn + n0) * Cc + c4 * 4;
#pragma unroll
  for (int i = 0; i < 4; i++) {
    store_h4(Qh + qbase + i * Cc, aq[i]);
    store_h4(Kp + kvbase + i * Cc, ak[i]);
    store_h4(V0 + kvbase + i * Cc, a0[i]);
    store_h4(V1 + kvbase + i * Cc, a1[i]);
  }
}

// 8-lane-per-point attention with folded output projection.
// Lane owns OUTPUT channels [4*c4, 4*c4+4) directly: PV accumulates the two
// per-head folded V streams weighted by (a0,a1); no out-proj matvec remains.
__global__ __launch_bounds__(256) void attn8_k(
    const int* __restrict__ li_coors, const int* __restrict__ ra_coors,
    const int* __restrict__ grids, const __half* __restrict__ Qh,
    const __half* __restrict__ Kp, const __half* __restrict__ V0,
    const __half* __restrict__ V1, const float* __restrict__ pv2g,
    const float* __restrict__ in_b1, const float* __restrict__ in_b2,
    const float* __restrict__ obias2, __half* __restrict__ out_pts) {
  int db = blockIdx.y;
  int dir = db >> 2, b = db & 3;
  __shared__ __align__(16) float spv[576];  // [h][l][c]
  __shared__ float sbk[Cc], sob[Cc];
  const float* ibp = dir == 0 ? in_b1 : in_b2;
  int t = threadIdx.x;
  for (int i = t; i < 576; i += 256) spv[i] = pv2g[dir * 576 + i];
  if (t < Cc) {
    sbk[t] = ibp[Cc + t];
    sob[t] = obias2[dir * Cc + t];
  }
  __syncthreads();
  int pt = t >> 3, c4 = t & 7;
  int n = blockIdx.x * 32 + pt;  // 625*32 == 20000 exact, no tail
  const int2* qcp =
      (const int2*)((dir == 0 ? li_coors : ra_coors) + (size_t)b * Nn * 2);
  int2 yx = qcp[n];
  int y = yx.x, x = yx.y;
  const int* g = grids + ((size_t)(1 - dir) * Bb + b) * HWp;
  const int DY[9] = {0, -1, 1, 0, -1, 1, 0, -1, 1};
  const int DX[9] = {0, 0, 0, 1, 1, 1, -1, -1, -1};
  // ---- phase 1: all 9 sel loads (independent, 1-deep; grid pre-filled)
  int sel[9];
#pragma unroll
  for (int l = 0; l < 9; l++) {
    int cy = y + DY[l], cx = x + DX[l];
    sel[l] = ((unsigned)cy < (unsigned)Hh && (unsigned)cx < (unsigned)Ww)
                 ? g[cy * Ww + cx]
                 : -1;
  }
  // ---- phase 2: issue all K/V0/V1 gathers (raw fp16, 8B/lane; 0 if invalid)
  size_t dbb = ((size_t)dir * Bb + b) * Nn * Cc;
  const __half* Kpb = Kp + dbb;
  const __half* V0b = V0 + dbb;
  const __half* V1b = V1 + dbb;
  float2 kr[9], v0r[9], v1r[9];
#pragma unroll
  for (int l = 0; l < 9; l++) {
    float2 kk = make_float2(0.f, 0.f);  // bit pattern 0 == fp16 zeros
    float2 v0v = make_float2(0.f, 0.f);
    float2 v1v = make_float2(0.f, 0.f);
    int se = sel[l];
    if (se >= 0) {
      size_t o = (size_t)se * Cc + c4 * 4;
      kk = *(const float2*)(Kpb + o);
      v0v = *(const float2*)(V0b + o);
      v1v = *(const float2*)(V1b + o);
    }
    kr[l] = kk;
    v0r[l] = v0v;
    v1r[l] = v1v;
  }
  float4 qh4 = cvt_h4(
      *(const float2*)(Qh + (((size_t)dir * Bb + b) * Nn + n) * Cc + c4 * 4));
  // invalid-slot score: qh . bk over the lane's head (DPP quad reduce)
  float4 bk4 = *(const float4*)(sbk + c4 * 4);
  float pb = qh4.x * bk4.x + qh4.y * bk4.y + qh4.z * bk4.z + qh4.w * bk4.w;
  pb = quad_add_xor1(pb);
  pb = quad_add_xor2(pb);
  // ---- phase 3: scores (own head) from registers
  float s[9];
#pragma unroll
  for (int l = 0; l < 9; l++) {
    float4 k4 = cvt_h4(kr[l]);
    float d = qh4.x * k4.x + qh4.y * k4.y + qh4.z * k4.z + qh4.w * k4.w;
    d = quad_add_xor1(d);
    d = quad_add_xor2(d);
    s[l] = 0.25f * (pb + d);
  }
  // softmax over 9 slots for the lane's head (invalid slots participate: s=pb/4)
  float m = s[0];
#pragma unroll
  for (int l = 1; l < 9; l++) m = fmaxf(m, s[l]);
  float sum = 0.f;
#pragma unroll
  for (int l = 0; l < 9; l++) {
    s[l] = __expf(s[l] - m);
    sum += s[l];
  }
  float rsum = 1.f / sum;
  float aown[9], aoth[9];
#pragma unroll
  for (int l = 0; l < 9; l++) aown[l] = s[l] * rsum;
#pragma unroll
  for (int l = 0; l < 9; l++) aoth[l] = __shfl_xor(aown[l], 4);
  // ---- phase 4: dual-head PV; lane's out channels = [4*c4..). hd = own head.
  int hd = c4 >> 2;
  float4 acc = *(const float4*)(sob + c4 * 4);  // out_b + B0 + B1
  const float* pv0 = spv + 0 * 288 + c4 * 4;
  const float* pv1 = spv + 1 * 288 + c4 * 4;
#pragma unroll
  for (int l = 0; l < 9; l++) {
    if (sel[l] >= 0) {
      float a0w = hd == 0 ? aown[l] : aoth[l];
      float a1w = hd == 0 ? aoth[l] : aown[l];
      float4 v0 = cvt_h4(v0r[l]);
      float4 v1 = cvt_h4(v1r[l]);
      float4 p0 = *(const float4*)(pv0 + l * 32);
      float4 p1 = *(const float4*)(pv1 + l * 32);
      acc.x += a0w * (v0.x + p0.x) + a1w * (v1.x + p1.x);
      acc.y += a0w * (v0.y + p0.y) + a1w * (v1.y + p1.y);
      acc.z += a0w * (v0.z + p0.z) + a1w * (v1.z + p1.z);
      acc.w += a0w * (v0.w + p0.w) + a1w * (v1.w + p1.w);
    }
  }
  store_h4(out_pts + (((size_t)dir * Bb + b) * Nn + n) * Cc + c4 * 4, acc);
}

// Inverted scatter: grid pre-filled. One thread per canvas pixel reads the
// point's 64B fp16 line, converts, writes fp32 channels (wave-coalesced).
__global__ __launch_bounds__(256) void scatter_k(
    const int* __restrict__ grids, const __half* __restrict__ out_pts,
    float* __restrict__ out) {
  int db = blockIdx.y;
  int dir = db >> 2, b = db & 3;
  int p = blockIdx.x * 256 + threadIdx.x;
  const int* gq = grids + ((size_t)dir * Bb + b) * HWp;
  int se = gq[p];
  float* ob = out + (((size_t)dir * Bb + b) * Cc) * HWp + p;
  if (se < 0) {
#pragma unroll
    for (int c = 0; c < Cc; c++) ob[(size_t)c * HWp] = 0.f;
  } else {
    const float4* sp =
        (const float4*)(out_pts + (((size_t)dir * Bb + b) * Nn + se) * Cc);
#pragma unroll
    for (int c8 = 0; c8 < 4; c8++) {
      H8 u;
      u.f4 = sp[c8];
#pragma unroll
      for (int k = 0; k < 4; k++) {
        float2 pr = __half22float2(u.h2[k]);
        ob[(size_t)(c8 * 8 + k * 2 + 0) * HWp] = pr.x;
        ob[(size_t)(c8 * 8 + k * 2 + 1) * HWp] = pr.y;
      }
    }
  }
}

extern "C" void kernel_launch(void* const* d_in, const int* in_sizes, int n_in,
                              void* d_out, int out_size, void* d_ws, size_t ws_size,
                              hipStream_t stream) {
  const float* li_feats = (const float*)d_in[0];
  const int* li_coors = (const int*)d_in[1];
  const float* ra_feats = (const float*)d_in[2];
  const int* ra_coors = (const int*)d_in[3];
  const float* pos = (const float*)d_in[4];
  const float* in_w1 = (const float*)d_in[5];
  const float* in_b1 = (const float*)d_in[6];
  const float* out_w1 = (const float*)d_in[7];
  const float* out_b1 = (const float*)d_in[8];
  const float* in_w2 = (const float*)d_in[9];
  const float* in_b2 = (const float*)d_in[10];
  const float* out_w2 = (const float*)d_in[11];
  const float* out_b2 = (const float*)d_in[12];

  char* ws = (char*)d_ws;
  size_t off = 0;
  int* grids = (int*)(ws + off);
  off += (size_t)2 * Bb * HWp * 4;  // 3,276,800 B
  __half* Qh = (__half*)(ws + off);
  off += (size_t)2 * Bb * Nn * Cc * 2;  // 10,240,000 B
  __half* Kp = (__half*)(ws + off);
  off += (size_t)2 * Bb * Nn * Cc * 2;
  __half* V0 = (__half*)(ws + off);
  off += (size_t)2 * Bb * Nn * Cc * 2;
  __half* V1 = (__half*)(ws + off);
  off += (size_t)2 * Bb * Nn * Cc * 2;
  __half* out_pts = (__half*)(ws + off);
  off += (size_t)2 * Bb * Nn * Cc * 2;
  float* Wvo = (float*)(ws + off);
  off += 2 * 2048 * 4;
  float* pv2g = (float*)(ws + off);
  off += 2 * 576 * 4;
  float* obias2 = (float*)(ws + off);
  off += 2 * Cc * 4;  // total ~54.5 MB

  prep_k<<<802, 256, 0, stream>>>(grids, pos, in_w1, in_b1, out_w1, out_b1,
                                  in_w2, in_b2, out_w2, out_b2, Wvo, pv2g,
                                  obias2);
  project_build_k<<<PROJ_TOTAL + BUILD_BLOCKS, 256, 0, stream>>>(
      li_feats, ra_feats, li_coors, ra_coors, in_w1, in_b1, in_w2, in_b2, Wvo,
      Qh, Kp, V0, V1, grids);
  dim3 ga(Nn / 32, 2 * Bb);
  attn8_k<<<ga, 256, 0, stream>>>(li_coors, ra_coors, grids, Qh, Kp, V0, V1,
                                  pv2g, in_b1, in_b2, obias2, out_pts);
  dim3 gs(HWp / 256, 2 * Bb);
  scatter_k<<<gs, 256, 0, stream>>>(grids, out_pts, (float*)d_out);
}

// Round 18
// 87.535 us; speedup vs baseline: 1.1914x; 1.0141x over previous
//
#include <hip/hip_runtime.h>
#include <hip/hip_fp16.h>

constexpr int Hh = 320, Ww = 320, Cc = 32, Bb = 4, Nn = 20000;
constexpr int HWp = Hh * Ww;

// DPP quad_perm helpers (VALU lane exchange within 4-lane quads; no DS pipe).
template <int CTRL>
__device__ __forceinline__ float dpp_mov(float x) {
  return __int_as_float(
      __builtin_amdgcn_update_dpp(0, __float_as_int(x), CTRL, 0xF, 0xF, true));
}
__device__ __forceinline__ float quad_add_xor1(float x) {
  return x + dpp_mov<0xB1>(x);
}
__device__ __forceinline__ float quad_add_xor2(float x) {
  return x + dpp_mov<0x4E>(x);
}

union H4 { __half2 h2[2]; float2 f2; };
union H8 { __half2 h2[4]; float4 f4; };

__device__ __forceinline__ void store_h4(__half* p, float4 v) {
  H4 u;
  u.h2[0] = __floats2half2_rn(v.x, v.y);
  u.h2[1] = __floats2half2_rn(v.z, v.w);
  *(float2*)p = u.f2;
}
__device__ __forceinline__ float4 cvt_h4(float2 raw) {
  H4 u;
  u.f2 = raw;
  float2 lo = __half22float2(u.h2[0]), hi = __half22float2(u.h2[1]);
  return make_float4(lo.x, lo.y, hi.x, hi.y);
}

// prep: blocks [0,800) fill grids with -1; blocks 800/801: per-dir fold
// constants. Wvo_h = ow[:,16h:16h+16] @ wv[16h:16h+16,:] (PER-HEAD fold of the
// output projection into V -- valid because each head has its own softmax).
// pv2[h][l][c] = pos_l @ Wvo_h.T ; obias2[c] = out_b[c] + sum_j bv[j]*ow[c,j].
__global__ __launch_bounds__(256) void prep_k(
    int* __restrict__ grids, const float* __restrict__ pos,
    const float* __restrict__ in_w1, const float* __restrict__ in_b1,
    const float* __restrict__ out_w1, const float* __restrict__ out_b1,
    const float* __restrict__ in_w2, const float* __restrict__ in_b2,
    const float* __restrict__ out_w2, const float* __restrict__ out_b2,
    float* __restrict__ Wvo, float* __restrict__ pv2g,
    float* __restrict__ obias2) {
  int bx = blockIdx.x;
  if (bx < 800) {
    int i = bx * 256 + threadIdx.x;  // 800*256 int4 = 2*4*HWp ints exactly
    ((int4*)grids)[i] = make_int4(-1, -1, -1, -1);
    return;
  }
  int dir = bx - 800;
  const float* iw = dir == 0 ? in_w1 : in_w2;
  const float* ib = dir == 0 ? in_b1 : in_b2;
  const float* owp = dir == 0 ? out_w1 : out_w2;
  const float* obp = dir == 0 ? out_b1 : out_b2;
  __shared__ float sow[1024], swv[1024], sW[2048];
  int t = threadIdx.x;
  for (int i = t; i < 1024; i += 256) {
    sow[i] = owp[i];
    swv[i] = iw[2 * Cc * Cc + i];  // wv rows of in_w
  }
  __syncthreads();
  for (int e = t; e < 2048; e += 256) {
    int h = e >> 10, idx = e & 1023;
    int c = idx >> 5, j = idx & 31;
    float acc = 0.f;
    for (int jj = 0; jj < 16; jj++)
      acc += sow[c * 32 + h * 16 + jj] * swv[(h * 16 + jj) * 32 + j];
    sW[e] = acc;
    Wvo[dir * 2048 + e] = acc;
  }
  __syncthreads();
  for (int e = t; e < 576; e += 256) {  // 2 heads x 9 slots x 32 ch
    int h = e / 288, rem = e - h * 288;
    int l = rem >> 5, c = rem & 31;
    float acc = 0.f;
    for (int j = 0; j < 32; j++) acc += pos[l * 32 + j] * sW[h * 1024 + c * 32 + j];
    pv2g[dir * 576 + e] = acc;
  }
  if (t < Cc) {
    float acc = obp[t];
    for (int j = 0; j < 32; j++) acc += ib[2 * Cc + j] * sow[t * 32 + j];
    obias2[dir * Cc + t] = acc;
  }
}

// Fused: blocks [0, PROJ_TOTAL) = Q/K/V0f/V1f projection (4 pts/thread, fp16
// stores; V0f/V1f are the per-head folded V); rest = build_grid (pre-filled).
constexpr int PROJ_BLOCKS_PER_SB = 157;              // ceil(20000/128)
constexpr int PROJ_TOTAL = PROJ_BLOCKS_PER_SB * 8;   // 1256
constexpr int BUILD_BLOCKS = 625;                    // 160000/256 exact

__global__ __launch_bounds__(256) void project_build_k(
    const float* __restrict__ li_feats, const float* __restrict__ ra_feats,
    const int* __restrict__ li_coors, const int* __restrict__ ra_coors,
    const float* __restrict__ in_w1, const float* __restrict__ in_b1,
    const float* __restrict__ in_w2, const float* __restrict__ in_b2,
    const float* __restrict__ Wvo,
    __half* __restrict__ Qh, __half* __restrict__ Kp,
    __half* __restrict__ V0, __half* __restrict__ V1,
    int* __restrict__ grids) {
  int bx = blockIdx.x;
  if (bx >= PROJ_TOTAL) {
    int idx = (bx - PROJ_TOTAL) * 256 + threadIdx.x;  // [0, 160000) exact
    int src = idx / (Bb * Nn);
    int r = idx - src * (Bb * Nn);
    int b = r / Nn, n = r - b * Nn;
    const int* c = (src == 0 ? li_coors : ra_coors) + ((size_t)b * Nn + n) * 2;
    grids[((size_t)src * Bb + b) * HWp + c[0] * Ww + c[1]] = n;
    return;
  }
  int sb = bx / PROJ_BLOCKS_PER_SB;
  int blk = bx - sb * PROJ_BLOCKS_PER_SB;
  int src = sb >> 2, b = sb & 3;
  // weights transposed, rows padded to 36 floats (9 float4) for bank spread
  __shared__ __align__(16) float wqT[32 * 36];
  __shared__ __align__(16) float wkT[32 * 36];
  __shared__ __align__(16) float w0T[32 * 36];
  __shared__ __align__(16) float w1T[32 * 36];
  __shared__ float bq[Cc];
  const float* wA = src == 0 ? in_w1 : in_w2;  // q weights: own direction
  const float* bA = src == 0 ? in_b1 : in_b2;
  const float* wB = src == 0 ? in_w2 : in_w1;  // k weights: other direction
  int dirkv = 1 - src;
  const float* Wf = Wvo + (size_t)dirkv * 2048;  // per-head folded V weights
  int t = threadIdx.x;
  for (int i = t; i < Cc * Cc; i += 256) {
    int c = i >> 5, j = i & 31;
    wqT[j * 36 + c] = wA[i];
    wkT[j * 36 + c] = wB[Cc * Cc + i];
    w0T[j * 36 + c] = Wf[i];
    w1T[j * 36 + c] = Wf[1024 + i];
  }
  if (t < Cc) bq[t] = bA[t];
  __syncthreads();
  int quad = t >> 3, c4 = t & 7;
  int n0 = blk * 128 + quad * 4;
  if (n0 + 4 > Nn) n0 = Nn - 4;  // tail clamp: redundant idempotent work
  const float* f = (src == 0 ? li_feats : ra_feats) + ((size_t)b * Nn + n0) * Cc;
  const float4* wq4 = (const float4*)wqT;
  const float4* wk4 = (const float4*)wkT;
  const float4* w04 = (const float4*)w0T;
  const float4* w14 = (const float4*)w1T;
  float4 bq4 = *(const float4*)(bq + c4 * 4);
  float4 aq[4], ak[4], a0[4], a1[4];
#pragma unroll
  for (int i = 0; i < 4; i++) {
    aq[i] = bq4;
    ak[i] = make_float4(0.f, 0.f, 0.f, 0.f);
    a0[i] = make_float4(0.f, 0.f, 0.f, 0.f);
    a1[i] = make_float4(0.f, 0.f, 0.f, 0.f);
  }
#pragma unroll
  for (int j4 = 0; j4 < 8; j4++) {
    float fjs[4][4];
#pragma unroll
    for (int i = 0; i < 4; i++) {
      float4 v = ((const float4*)(f + i * Cc))[j4];
      fjs[i][0] = v.x; fjs[i][1] = v.y; fjs[i][2] = v.z; fjs[i][3] = v.w;
    }
#pragma unroll
    for (int u = 0; u < 4; u++) {
      int j = j4 * 4 + u;
      float4 q4 = wq4[j * 9 + c4];
      float4 k4 = wk4[j * 9 + c4];
      float4 v04 = w04[j * 9 + c4];
      float4 v14 = w14[j * 9 + c4];
#pragma unroll
      for (int i = 0; i < 4; i++) {
        float fj = fjs[i][u];
        aq[i].x += fj * q4.x; aq[i].y += fj * q4.y;
        aq[i].z += fj * q4.z; aq[i].w += fj * q4.w;
        ak[i].x += fj * k4.x; ak[i].y += fj * k4.y;
        ak[i].z += fj * k4.z; ak[i].w += fj * k4.w;
        a0[i].x += fj * v04.x; a0[i].y += fj * v04.y;
        a0[i].z += fj * v04.z; a0[i].w += fj * v04.w;
        a1[i].x += fj * v14.x; a1[i].y += fj * v14.y;
        a1[i].z += fj * v14.z; a1[i].w += fj * v14.w;
      }
    }
  }
  size_t qbase = (((size_t)src * Bb + b) * Nn + n0) * Cc + c4 * 4;
  size_t kvbase = (((size_t)dirkv * Bb + b) * Nn + n0) * Cc + c4 * 4;
#pragma unroll
  for (int i = 0; i < 4; i++) {
    store_h4(Qh + qbase + i * Cc, aq[i]);
    store_h4(Kp + kvbase + i * Cc, ak[i]);
    store_h4(V0 + kvbase + i * Cc, a0[i]);
    store_h4(V1 + kvbase + i * Cc, a1[i]);
  }
}

// 8-lane-per-point attention with folded output projection.
// XCD-partitioned: db = blockIdx.x % 8 so all blocks of one (dir,b) land on
// one XCD (round-robin dispatch) -> its K/V0/V1 slices (~3.8 MB, 9x reuse)
// stay resident in that XCD's 4 MB L2; gathers become L2-hits instead of L3.
__global__ __launch_bounds__(256) void attn8_k(
    const int* __restrict__ li_coors, const int* __restrict__ ra_coors,
    const int* __restrict__ grids, const __half* __restrict__ Qh,
    const __half* __restrict__ Kp, const __half* __restrict__ V0,
    const __half* __restrict__ V1, const float* __restrict__ pv2g,
    const float* __restrict__ in_b1, const float* __restrict__ in_b2,
    const float* __restrict__ obias2, __half* __restrict__ out_pts) {
  int db = blockIdx.x & 7;   // XCD-pinned (dir,b)
  int bx = blockIdx.x >> 3;  // point tile [0, 625)
  int dir = db >> 2, b = db & 3;
  __shared__ __align__(16) float spv[576];  // [h][l][c]
  __shared__ float sbk[Cc], sob[Cc];
  const float* ibp = dir == 0 ? in_b1 : in_b2;
  int t = threadIdx.x;
  for (int i = t; i < 576; i += 256) spv[i] = pv2g[dir * 576 + i];
  if (t < Cc) {
    sbk[t] = ibp[Cc + t];
    sob[t] = obias2[dir * Cc + t];
  }
  __syncthreads();
  int pt = t >> 3, c4 = t & 7;
  int n = bx * 32 + pt;  // 625*32 == 20000 exact, no tail
  const int2* qcp =
      (const int2*)((dir == 0 ? li_coors : ra_coors) + (size_t)b * Nn * 2);
  int2 yx = qcp[n];
  int y = yx.x, x = yx.y;
  const int* g = grids + ((size_t)(1 - dir) * Bb + b) * HWp;
  const int DY[9] = {0, -1, 1, 0, -1, 1, 0, -1, 1};
  const int DX[9] = {0, 0, 0, 1, 1, 1, -1, -1, -1};
  // ---- phase 1: all 9 sel loads (independent, 1-deep; grid pre-filled)
  int sel[9];
#pragma unroll
  for (int l = 0; l < 9; l++) {
    int cy = y + DY[l], cx = x + DX[l];
    sel[l] = ((unsigned)cy < (unsigned)Hh && (unsigned)cx < (unsigned)Ww)
                 ? g[cy * Ww + cx]
                 : -1;
  }
  // ---- phase 2: issue all K/V0/V1 gathers (raw fp16, 8B/lane; 0 if invalid)
  size_t dbb = ((size_t)dir * Bb + b) * Nn * Cc;
  const __half* Kpb = Kp + dbb;
  const __half* V0b = V0 + dbb;
  const __half* V1b = V1 + dbb;
  float2 kr[9], v0r[9], v1r[9];
#pragma unroll
  for (int l = 0; l < 9; l++) {
    float2 kk = make_float2(0.f, 0.f);  // bit pattern 0 == fp16 zeros
    float2 v0v = make_float2(0.f, 0.f);
    float2 v1v = make_float2(0.f, 0.f);
    int se = sel[l];
    if (se >= 0) {
      size_t o = (size_t)se * Cc + c4 * 4;
      kk = *(const float2*)(Kpb + o);
      v0v = *(const float2*)(V0b + o);
      v1v = *(const float2*)(V1b + o);
    }
    kr[l] = kk;
    v0r[l] = v0v;
    v1r[l] = v1v;
  }
  float4 qh4 = cvt_h4(
      *(const float2*)(Qh + (((size_t)dir * Bb + b) * Nn + n) * Cc + c4 * 4));
  // invalid-slot score: qh . bk over the lane's head (DPP quad reduce)
  float4 bk4 = *(const float4*)(sbk + c4 * 4);
  float pb = qh4.x * bk4.x + qh4.y * bk4.y + qh4.z * bk4.z + qh4.w * bk4.w;
  pb = quad_add_xor1(pb);
  pb = quad_add_xor2(pb);
  // ---- phase 3: scores (own head) from registers
  float s[9];
#pragma unroll
  for (int l = 0; l < 9; l++) {
    float4 k4 = cvt_h4(kr[l]);
    float d = qh4.x * k4.x + qh4.y * k4.y + qh4.z * k4.z + qh4.w * k4.w;
    d = quad_add_xor1(d);
    d = quad_add_xor2(d);
    s[l] = 0.25f * (pb + d);
  }
  // softmax over 9 slots for the lane's head (invalid slots participate: s=pb/4)
  float m = s[0];
#pragma unroll
  for (int l = 1; l < 9; l++) m = fmaxf(m, s[l]);
  float sum = 0.f;
#pragma unroll
  for (int l = 0; l < 9; l++) {
    s[l] = __expf(s[l] - m);
    sum += s[l];
  }
  float rsum = 1.f / sum;
  float aown[9], aoth[9];
#pragma unroll
  for (int l = 0; l < 9; l++) aown[l] = s[l] * rsum;
#pragma unroll
  for (int l = 0; l < 9; l++) aoth[l] = __shfl_xor(aown[l], 4);
  // ---- phase 4: dual-head PV; lane's out channels = [4*c4..). hd = own head.
  int hd = c4 >> 2;
  float4 acc = *(const float4*)(sob + c4 * 4);  // out_b + B0 + B1
  const float* pv0 = spv + 0 * 288 + c4 * 4;
  const float* pv1 = spv + 1 * 288 + c4 * 4;
#pragma unroll
  for (int l = 0; l < 9; l++) {
    if (sel[l] >= 0) {
      float a0w = hd == 0 ? aown[l] : aoth[l];
      float a1w = hd == 0 ? aoth[l] : aown[l];
      float4 v0 = cvt_h4(v0r[l]);
      float4 v1 = cvt_h4(v1r[l]);
      float4 p0 = *(const float4*)(pv0 + l * 32);
      float4 p1 = *(const float4*)(pv1 + l * 32);
      acc.x += a0w * (v0.x + p0.x) + a1w * (v1.x + p1.x);
      acc.y += a0w * (v0.y + p0.y) + a1w * (v1.y + p1.y);
      acc.z += a0w * (v0.z + p0.z) + a1w * (v1.z + p1.z);
      acc.w += a0w * (v0.w + p0.w) + a1w * (v1.w + p1.w);
    }
  }
  store_h4(out_pts + (((size_t)dir * Bb + b) * Nn + n) * Cc + c4 * 4, acc);
}

// Inverted scatter, XCD-partitioned like attn8 (out_pts slice L2-resident).
// One thread per canvas pixel; channel stores are wave-coalesced full lines.
__global__ __launch_bounds__(256) void scatter_k(
    const int* __restrict__ grids, const __half* __restrict__ out_pts,
    float* __restrict__ out) {
  int db = blockIdx.x & 7;   // XCD-pinned (dir,b)
  int bx = blockIdx.x >> 3;  // pixel tile [0, 400)
  int dir = db >> 2, b = db & 3;
  int p = bx * 256 + threadIdx.x;
  const int* gq = grids + ((size_t)dir * Bb + b) * HWp;
  int se = gq[p];
  float* ob = out + (((size_t)dir * Bb + b) * Cc) * HWp + p;
  if (se < 0) {
#pragma unroll
    for (int c = 0; c < Cc; c++) ob[(size_t)c * HWp] = 0.f;
  } else {
    const float4* sp =
        (const float4*)(out_pts + (((size_t)dir * Bb + b) * Nn + se) * Cc);
#pragma unroll
    for (int c8 = 0; c8 < 4; c8++) {
      H8 u;
      u.f4 = sp[c8];
#pragma unroll
      for (int k = 0; k < 4; k++) {
        float2 pr = __half22float2(u.h2[k]);
        ob[(size_t)(c8 * 8 + k * 2 + 0) * HWp] = pr.x;
        ob[(size_t)(c8 * 8 + k * 2 + 1) * HWp] = pr.y;
      }
    }
  }
}

extern "C" void kernel_launch(void* const* d_in, const int* in_sizes, int n_in,
                              void* d_out, int out_size, void* d_ws, size_t ws_size,
                              hipStream_t stream) {
  const float* li_feats = (const float*)d_in[0];
  const int* li_coors = (const int*)d_in[1];
  const float* ra_feats = (const float*)d_in[2];
  const int* ra_coors = (const int*)d_in[3];
  const float* pos = (const float*)d_in[4];
  const float* in_w1 = (const float*)d_in[5];
  const float* in_b1 = (const float*)d_in[6];
  const float* out_w1 = (const float*)d_in[7];
  const float* out_b1 = (const float*)d_in[8];
  const float* in_w2 = (const float*)d_in[9];
  const float* in_b2 = (const float*)d_in[10];
  const float* out_w2 = (const float*)d_in[11];
  const float* out_b2 = (const float*)d_in[12];

  char* ws = (char*)d_ws;
  size_t off = 0;
  int* grids = (int*)(ws + off);
  off += (size_t)2 * Bb * HWp * 4;  // 3,276,800 B
  __half* Qh = (__half*)(ws + off);
  off += (size_t)2 * Bb * Nn * Cc * 2;  // 10,240,000 B
  __half* Kp = (__half*)(ws + off);
  off += (size_t)2 * Bb * Nn * Cc * 2;
  __half* V0 = (__half*)(ws + off);
  off += (size_t)2 * Bb * Nn * Cc * 2;
  __half* V1 = (__half*)(ws + off);
  off += (size_t)2 * Bb * Nn * Cc * 2;
  __half* out_pts = (__half*)(ws + off);
  off += (size_t)2 * Bb * Nn * Cc * 2;
  float* Wvo = (float*)(ws + off);
  off += 2 * 2048 * 4;
  float* pv2g = (float*)(ws + off);
  off += 2 * 576 * 4;
  float* obias2 = (float*)(ws + off);
  off += 2 * Cc * 4;  // total ~54.5 MB

  prep_k<<<802, 256, 0, stream>>>(grids, pos, in_w1, in_b1, out_w1, out_b1,
                                  in_w2, in_b2, out_w2, out_b2, Wvo, pv2g,
                                  obias2);
  project_build_k<<<PROJ_TOTAL + BUILD_BLOCKS, 256, 0, stream>>>(
      li_feats, ra_feats, li_coors, ra_coors, in_w1, in_b1, in_w2, in_b2, Wvo,
      Qh, Kp, V0, V1, grids);
  attn8_k<<<(Nn / 32) * 8, 256, 0, stream>>>(li_coors, ra_coors, grids, Qh, Kp,
                                             V0, V1, pv2g, in_b1, in_b2, obias2,
                                             out_pts);
  scatter_k<<<(HWp / 256) * 8, 256, 0, stream>>>(grids, out_pts,
                                                 (float*)d_out);
}